// Round 4
// baseline (358.413 us; speedup 1.0000x reference)
//
#include <hip/hip_runtime.h>
#include <hip/hip_bf16.h>
#include <math.h>

typedef unsigned short u16;
typedef __attribute__((ext_vector_type(8))) short bf16x8;
typedef __attribute__((ext_vector_type(4))) float f32x4;
typedef __attribute__((ext_vector_type(4))) unsigned short u16x4;

#define B_ 8
#define S_ 2048
#define T_ 16384
#define D_ 1024
#define H_ 16
#define EPS_ 1e-5f

__device__ __forceinline__ u16 f2bf(float f) {
    __hip_bfloat16 h = __float2bfloat16(f);
    union { __hip_bfloat16 h; u16 u; } cv; cv.h = h; return cv.u;
}
__device__ __forceinline__ float bf2f(u16 u) {
    union { u16 u; __hip_bfloat16 h; } cv; cv.u = u; return __bfloat162float(cv.h);
}

// ---------- K0a: W' = diag(rln_g[:1024])*r_w1[:1024] transposed + split bf16;
//            c1/c2 partials over all 2048 rows ----------
__global__ __launch_bounds__(256) void k0a(const float* __restrict__ rw1,
        const float* __restrict__ rlng, const float* __restrict__ rlnb,
        u16* __restrict__ whiT, u16* __restrict__ wloT,
        float* __restrict__ c1part, float* __restrict__ c2part) {
    int nb = blockIdx.x, kb = blockIdx.y;   // nb<16, kb<32
    int t = threadIdx.x;
    int nl = t & 63, kq = t >> 6;
    int n0 = nb * 64, k0 = kb * 64;
    __shared__ float ld[64][65];
    __shared__ float red[2][4][64];
    float a1 = 0.f, a2 = 0.f;
    #pragma unroll
    for (int r = 0; r < 16; ++r) {
        int kl = r * 4 + kq;
        int k = k0 + kl, n = n0 + nl;
        float w0 = rw1[(size_t)k * 1024 + n];
        ld[kl][nl] = w0;
        a1 += rlng[k] * w0;
        a2 += rlnb[k] * w0;
    }
    red[0][kq][nl] = a1;
    red[1][kq][nl] = a2;
    __syncthreads();
    if (t < 64) {
        c1part[(size_t)kb * 1024 + n0 + t] = red[0][0][t] + red[0][1][t] + red[0][2][t] + red[0][3][t];
        c2part[(size_t)kb * 1024 + n0 + t] = red[1][0][t] + red[1][1][t] + red[1][2][t] + red[1][3][t];
    }
    if (kb < 16) {
        #pragma unroll
        for (int r = 0; r < 16; ++r) {
            int nl2 = r * 4 + kq;
            int k = k0 + nl, n = n0 + nl2;
            float w0 = ld[nl][nl2] * rlng[k];
            u16 hi = f2bf(w0);
            float lo = w0 - bf2f(hi);
            whiT[(size_t)n * 1024 + k] = hi;
            wloT[(size_t)n * 1024 + k] = f2bf(lo);
        }
    }
}

// ---------- K1: pool LN pass over x; per-token sums; x -> split bf16 ----------
__global__ __launch_bounds__(256) void k1(const float* __restrict__ x,
        u16* __restrict__ xhi, u16* __restrict__ xlo,
        float* __restrict__ sx, float* __restrict__ sxx, float* __restrict__ gpart) {
    int blk = blockIdx.x;                  // 256 blocks
    int b = blk >> 5, chunk = blk & 31;
    int tid = threadIdx.x, w = tid >> 6, lane = tid & 63;
    __shared__ float lacc[4][1024];
    float acc[4][4];
    #pragma unroll
    for (int j = 0; j < 4; ++j)
        #pragma unroll
        for (int c = 0; c < 4; ++c) acc[j][c] = 0.f;

    for (int i = 0; i < 16; ++i) {
        int s = chunk * 64 + i * 4 + w;
        size_t tok = (size_t)b * S_ + s;
        size_t base = tok * D_;
        float4 v[4];
        float sum = 0.f, ssq = 0.f;
        #pragma unroll
        for (int j = 0; j < 4; ++j) {
            v[j] = *(const float4*)&x[base + j * 256 + lane * 4];
            sum += v[j].x + v[j].y + v[j].z + v[j].w;
            ssq += v[j].x * v[j].x + v[j].y * v[j].y + v[j].z * v[j].z + v[j].w * v[j].w;
        }
        #pragma unroll
        for (int m = 1; m < 64; m <<= 1) { sum += __shfl_xor(sum, m); ssq += __shfl_xor(ssq, m); }
        float mean = sum * (1.f / 1024.f);
        float var = ssq * (1.f / 1024.f) - mean * mean;
        float rstd = rsqrtf(var + EPS_);
        if (lane == 0) { sx[tok] = sum; sxx[tok] = ssq; }
        #pragma unroll
        for (int j = 0; j < 4; ++j) {
            float xs[4] = { v[j].x, v[j].y, v[j].z, v[j].w };
            u16 hs[4], ls[4];
            #pragma unroll
            for (int c = 0; c < 4; ++c) {
                acc[j][c] += (xs[c] - mean) * rstd;
                u16 h = f2bf(xs[c]);
                hs[c] = h;
                ls[c] = f2bf(xs[c] - bf2f(h));
            }
            size_t o = base + j * 256 + lane * 4;
            *(u16x4*)&xhi[o] = (u16x4){ hs[0], hs[1], hs[2], hs[3] };
            *(u16x4*)&xlo[o] = (u16x4){ ls[0], ls[1], ls[2], ls[3] };
        }
    }
    #pragma unroll
    for (int j = 0; j < 4; ++j)
        #pragma unroll
        for (int c = 0; c < 4; ++c) lacc[w][j * 256 + lane * 4 + c] = acc[j][c];
    __syncthreads();
    for (int q = 0; q < 4; ++q) {
        int n = q * 256 + tid;
        gpart[((size_t)b * 32 + chunk) * 1024 + n] =
            lacc[0][n] + lacc[1][n] + lacc[2][n] + lacc[3][n];
    }
}

// ---------- kgemv_g: fused g-vector build (reduce gpart) + split-K GEMV with inp_w ----------
__global__ __launch_bounds__(256) void kgemv_g(const float* __restrict__ gpart,
        const float* __restrict__ pg, const float* __restrict__ pb,
        const float* __restrict__ W, float* __restrict__ part) {
    int t = threadIdx.x;
    int n = blockIdx.x * 256 + t;
    int k0 = blockIdx.y * 32;
    __shared__ float sg[8][32];
    {
        int b = t >> 5, k = t & 31;
        float s = 0.f;
        #pragma unroll 8
        for (int p = 0; p < 32; ++p) s += gpart[((size_t)b * 32 + p) * 1024 + k0 + k];
        sg[b][k] = s * (1.f / 2048.f) * pg[k0 + k] + pb[k0 + k];
    }
    __syncthreads();
    float acc[8] = {};
    #pragma unroll
    for (int k = 0; k < 32; ++k) {
        float wv = W[(size_t)(k0 + k) * 1024 + n];
        #pragma unroll
        for (int b = 0; b < 8; ++b) acc[b] += sg[b][k] * wv;
    }
    #pragma unroll
    for (int b = 0; b < 8; ++b)
        part[((size_t)blockIdx.y * 8 + b) * 1024 + n] = acc[b];
}

// ---------- split-K GEMV: part[kb][b][n] = sum_{k in slice} in[b][k]*scale[k]*W[k][n] ----------
__global__ __launch_bounds__(256) void kgemv_split(const float* __restrict__ in,
        const float* __restrict__ W, const float* __restrict__ scale,
        float* __restrict__ part) {
    int t = threadIdx.x;
    int n = blockIdx.x * 256 + t;
    int k0 = blockIdx.y * 32;
    __shared__ float sg[8][32];
    {
        int b = t >> 5, k = t & 31;
        float v = in[b * 1024 + k0 + k];
        if (scale) v *= scale[k0 + k];
        sg[b][k] = v;
    }
    __syncthreads();
    float acc[8] = {};
    #pragma unroll
    for (int k = 0; k < 32; ++k) {
        float wv = W[(size_t)(k0 + k) * 1024 + n];
        #pragma unroll
        for (int b = 0; b < 8; ++b) acc[b] += sg[b][k] * wv;
    }
    #pragma unroll
    for (int b = 0; b < 8; ++b)
        part[((size_t)blockIdx.y * 8 + b) * 1024 + n] = acc[b];
}

// ---------- kgemv2_f: fused xctrl reduce(+bias) + dual split-K GEMV for W_z / W_h ----------
__global__ __launch_bounds__(256) void kgemv2_f(const float* __restrict__ partIn,
        const float* __restrict__ bias,
        const float* __restrict__ Wz, const float* __restrict__ Wh,
        float* __restrict__ zpart, float* __restrict__ hpart) {
    int t = threadIdx.x;
    int n = blockIdx.x * 256 + t;
    int k0 = blockIdx.y * 32;
    __shared__ float sg[8][32];
    {
        int b = t >> 5, k = t & 31;
        float s = bias[k0 + k];
        #pragma unroll 8
        for (int p = 0; p < 32; ++p) s += partIn[((size_t)p * 8 + b) * 1024 + k0 + k];
        sg[b][k] = s;
    }
    __syncthreads();
    float az[8] = {}, ah[8] = {};
    #pragma unroll
    for (int k = 0; k < 32; ++k) {
        size_t o = (size_t)(k0 + k) * 1024 + n;
        float wz = Wz[o];
        float wh = Wh[o];
        #pragma unroll
        for (int b = 0; b < 8; ++b) { az[b] += sg[b][k] * wz; ah[b] += sg[b][k] * wh; }
    }
    #pragma unroll
    for (int b = 0; b < 8; ++b) {
        size_t o = ((size_t)blockIdx.y * 8 + b) * 1024 + n;
        zpart[o] = az[b];
        hpart[o] = ah[b];
    }
}

// ---------- k3b reduce + gate + h-LayerNorm fused (grid 8, one block per b) ----------
__global__ __launch_bounds__(256) void k3b_red_ln(const float* __restrict__ zpart,
        const float* __restrict__ hpart, const float* __restrict__ bz,
        const float* __restrict__ bh, const float* __restrict__ state,
        const float* __restrict__ lg, const float* __restrict__ lb,
        float* __restrict__ hnew, float* __restrict__ outh,
        float* __restrict__ shb, float* __restrict__ shhb) {
    int b = blockIdx.x, tid = threadIdx.x;
    int w = tid >> 6, lane = tid & 63;
    __shared__ float rbuf[4][2];
    float hp[4];
    float sum = 0.f, ssq = 0.f;
    #pragma unroll
    for (int q = 0; q < 4; ++q) {
        int n = q * 256 + tid;
        float az = bz[n], ah = bh[n];
        #pragma unroll 8
        for (int p = 0; p < 32; ++p) {
            size_t o = ((size_t)p * 8 + b) * 1024 + n;
            az += zpart[o];
            ah += hpart[o];
        }
        float z = 1.f / (1.f + expf(-az));
        float hc = tanhf(ah);
        float v = (1.f - z) * state[(size_t)b * 1024 + n] + z * hc;
        hp[q] = v; sum += v; ssq += v * v;
    }
    #pragma unroll
    for (int m = 1; m < 64; m <<= 1) { sum += __shfl_xor(sum, m); ssq += __shfl_xor(ssq, m); }
    if (lane == 0) { rbuf[w][0] = sum; rbuf[w][1] = ssq; }
    __syncthreads();
    sum = rbuf[0][0] + rbuf[1][0] + rbuf[2][0] + rbuf[3][0];
    ssq = rbuf[0][1] + rbuf[1][1] + rbuf[2][1] + rbuf[3][1];
    float mean = sum * (1.f / 1024.f);
    float var = ssq * (1.f / 1024.f) - mean * mean;
    float rstd = rsqrtf(var + EPS_);
    float s2 = 0.f, q2 = 0.f;
    #pragma unroll
    for (int q = 0; q < 4; ++q) {
        int n = q * 256 + tid;
        float h = (hp[q] - mean) * rstd * lg[n] + lb[n];
        hnew[(size_t)b * 1024 + n] = h;
        outh[(size_t)b * 1024 + n] = h;
        s2 += h; q2 += h * h;
    }
    #pragma unroll
    for (int m = 1; m < 64; m <<= 1) { s2 += __shfl_xor(s2, m); q2 += __shfl_xor(q2, m); }
    __syncthreads();
    if (lane == 0) { rbuf[w][0] = s2; rbuf[w][1] = q2; }
    __syncthreads();
    if (tid == 0) {
        shb[b] = rbuf[0][0] + rbuf[1][0] + rbuf[2][0] + rbuf[3][0];
        shhb[b] = rbuf[0][1] + rbuf[1][1] + rbuf[2][1] + rbuf[3][1];
    }
}

// ---------- K5: 8-phase 256x256 counted-vmcnt split-bf16 GEMM (flat K'=3072),
//            fused router-LN + GELU + chunked partial-logits epilogue ----------
__device__ __forceinline__ void gl16(const void* g, void* l) {
    __builtin_amdgcn_global_load_lds((const __attribute__((address_space(1))) void*)g,
                                     (__attribute__((address_space(3))) void*)l, 16, 0, 0);
}

// stage one unit = (one matrix, one khalf) = 16KB via 2 gl16/thread
#define STAGEU(PL, GB, ROFF) do { \
    _Pragma("unroll") \
    for (int i_ = 0; i_ < 2; ++i_) { \
        int ch_ = tid + 512 * i_; \
        gl16((PL) + (GB) + (size_t)(ch_ >> 2) * 1024 + (ch_ & 3) * 8, \
             smem + (ROFF) + ch_ * 16); \
    } } while (0)

// one phase: stage-issue || ds-read frags, [vmcnt(N)], barrier, 16 MFMA, barrier
#define PHASE(KK, MH, STG, VMN) do { \
    STG; \
    { const u16* pA_ = (const u16*)(smem + buf * 32768 + (KK) * 16384); \
      const u16* pB_ = (const u16*)(smem + 65536 + buf * 32768 + (KK) * 16384); \
      _Pragma("unroll") \
      for (int mi_ = 0; mi_ < 4; ++mi_) \
          fa[mi_] = *(const bf16x8*)&pA_[(wm * 128 + ((MH) * 4 + mi_) * 16 + l16) * 32 + lq * 8]; \
      if ((MH) == 0) { \
          _Pragma("unroll") \
          for (int ni_ = 0; ni_ < 4; ++ni_) \
              fb[ni_] = *(const bf16x8*)&pB_[(wn * 64 + ni_ * 16 + l16) * 32 + lq * 8]; \
      } } \
    if ((VMN) == 4) { asm volatile("s_waitcnt vmcnt(4)" ::: "memory"); } \
    else if ((VMN) == 0) { asm volatile("s_waitcnt vmcnt(0)" ::: "memory"); } \
    __builtin_amdgcn_sched_barrier(0); \
    __builtin_amdgcn_s_barrier(); \
    __builtin_amdgcn_sched_barrier(0); \
    __builtin_amdgcn_s_setprio(1); \
    _Pragma("unroll") \
    for (int mi_ = 0; mi_ < 4; ++mi_) { \
        _Pragma("unroll") \
        for (int ni_ = 0; ni_ < 4; ++ni_) \
            acc[(MH) * 4 + mi_][ni_] = __builtin_amdgcn_mfma_f32_16x16x32_bf16( \
                fa[mi_], fb[ni_], acc[(MH) * 4 + mi_][ni_], 0, 0, 0); \
    } \
    __builtin_amdgcn_s_setprio(0); \
    __builtin_amdgcn_sched_barrier(0); \
    __builtin_amdgcn_s_barrier(); \
    __builtin_amdgcn_sched_barrier(0); \
} while (0)

__global__ __launch_bounds__(512, 2) void k5_gemm(
        const u16* __restrict__ xhi, const u16* __restrict__ xlo,
        const u16* __restrict__ whiT, const u16* __restrict__ wloT,
        const float* __restrict__ sx, const float* __restrict__ sxx,
        const float* __restrict__ shb, const float* __restrict__ shhb,
        const float* __restrict__ vpart, const float* __restrict__ c1part,
        const float* __restrict__ c2part, const float* __restrict__ rb1,
        const float* __restrict__ rw2, float* __restrict__ lpart) {
    // LDS: A[2 dbuf][2 khalf][256 rows][32 k] u16 = 64KB, then B same = 64KB (total 128KB)
    // epilogue reuse: shid[64][260] f32 (66560B) + red[64][8][16] f32 (32KB)
    __shared__ unsigned char smem[131072];

    int bid = blockIdx.x;
    int o = (bid & 7) * 32 + (bid >> 3);   // XCD-bijective: 4 nb-blocks per mb on one XCD
    int nb = o & 3, mb = o >> 2;           // nb<4 (256 cols), mb<64 (256 tokens)
    int tid = threadIdx.x;
    int lane = tid & 63, wid = tid >> 6;
    int wm = wid >> 2, wn = wid & 3;       // 2M x 4N waves
    int l16 = lane & 15, lq = lane >> 4;

    f32x4 acc[8][4] = {};
    bf16x8 fa[4], fb[4];

    size_t aBase = (size_t)mb * 256 * 1024;
    size_t bBase = (size_t)nb * 256 * 1024;

    // prologue: stage tile 0 (seg 0: xhi x whiT) into buf 0, both khalves
    STAGEU(xhi, aBase, 0);
    STAGEU(whiT, bBase, 65536);
    STAGEU(xhi, aBase + 32, 16384);
    STAGEU(whiT, bBase + 32, 65536 + 16384);
    asm volatile("s_waitcnt vmcnt(4)" ::: "memory");   // khalf0 of A,B landed
    __builtin_amdgcn_sched_barrier(0);
    __builtin_amdgcn_s_barrier();
    __builtin_amdgcn_sched_barrier(0);

    // K' = 3072: tile t in [0,48); seg = t>>4 selects planes
    for (int t = 0; t < 47; ++t) {
        int buf = t & 1;
        int so = (buf ^ 1) * 32768;
        int tt = t + 1;
        const u16* Ap = (tt < 32) ? xhi : xlo;
        const u16* Bp = (tt >= 16 && tt < 32) ? wloT : whiT;
        size_t gA = aBase + (size_t)(tt & 15) * 64;
        size_t gB = bBase + (size_t)(tt & 15) * 64;
        PHASE(0, 0, STAGEU(Ap, gA, so), -1);
        PHASE(0, 1, STAGEU(Bp, gB, 65536 + so), 4);
        PHASE(1, 0, STAGEU(Ap, gA + 32, so + 16384), -1);
        PHASE(1, 1, STAGEU(Bp, gB + 32, 65536 + so + 16384), 4);
    }
    {   // peeled final tile t=47 (no staging; drain before khalf1)
        int buf = 1;
        PHASE(0, 0, (void)0, -1);
        PHASE(0, 1, (void)0, 0);
        PHASE(1, 0, (void)0, -1);
        PHASE(1, 1, (void)0, -1);
    }

    // ---- epilogue: 4 chunks x 64 rows through LDS ----
    int token0 = mb * 256;
    int bidx = mb >> 3;
    float vn[4], c1n[4], dn[4];
    #pragma unroll
    for (int nf = 0; nf < 4; ++nf) {
        int n = nb * 256 + wn * 64 + nf * 16 + l16;
        float sv = 0.f, s1 = 0.f, s2 = 0.f;
        for (int p = 0; p < 32; ++p) {
            sv += vpart[((size_t)p * 8 + bidx) * 1024 + n];
            s1 += c1part[(size_t)p * 1024 + n];
            s2 += c2part[(size_t)p * 1024 + n];
        }
        vn[nf] = sv; c1n[nf] = s1; dn[nf] = s2 + rb1[n];
    }
    float sH = shb[bidx], sHH = shhb[bidx];
    float* shid = (float*)smem;              // [64][260]
    float* red  = (float*)(smem + 66560);    // [64][8][16]

    #pragma unroll
    for (int c = 0; c < 4; ++c) {
        __syncthreads();
        if (wm == (c >> 1)) {
            #pragma unroll
            for (int mf2 = 0; mf2 < 4; ++mf2) {
                #pragma unroll
                for (int r = 0; r < 4; ++r) {
                    int rr = mf2 * 16 + lq * 4 + r;
                    int tok = token0 + c * 64 + rr;
                    float mean = (sx[tok] + sH) * (1.f / 2048.f);
                    float var = (sxx[tok] + sHH) * (1.f / 2048.f) - mean * mean;
                    float p = rsqrtf(var + EPS_);
                    float q = -mean * p;
                    #pragma unroll
                    for (int nf = 0; nf < 4; ++nf) {
                        int col = wn * 64 + nf * 16 + l16;
                        float pre = p * (acc[(c & 1) * 4 + mf2][nf][r] + vn[nf]) + q * c1n[nf] + dn[nf];
                        shid[rr * 260 + col] = 0.5f * pre * (1.f + erff(pre * 0.70710678118f));
                    }
                }
            }
        }
        __syncthreads();
        {   // partial logits over this block's 256 cols
            int row = tid >> 3, t8 = tid & 7;
            float a16[16];
            #pragma unroll
            for (int h = 0; h < 16; ++h) a16[h] = 0.f;
            #pragma unroll 4
            for (int cc = 0; cc < 32; ++cc) {
                int col = t8 * 32 + cc;
                float hv = shid[row * 260 + col];
                const float* w2p = rw2 + (size_t)(nb * 256 + col) * 16;
                float4 w0 = *(const float4*)(w2p);
                float4 w1 = *(const float4*)(w2p + 4);
                float4 w2 = *(const float4*)(w2p + 8);
                float4 w3 = *(const float4*)(w2p + 12);
                a16[0] += hv * w0.x; a16[1] += hv * w0.y; a16[2] += hv * w0.z; a16[3] += hv * w0.w;
                a16[4] += hv * w1.x; a16[5] += hv * w1.y; a16[6] += hv * w1.z; a16[7] += hv * w1.w;
                a16[8] += hv * w2.x; a16[9] += hv * w2.y; a16[10] += hv * w2.z; a16[11] += hv * w2.w;
                a16[12] += hv * w3.x; a16[13] += hv * w3.y; a16[14] += hv * w3.z; a16[15] += hv * w3.w;
            }
            #pragma unroll
            for (int h = 0; h < 16; ++h) red[(row * 8 + t8) * 16 + h] = a16[h];
        }
        __syncthreads();
        {
            int row = tid >> 3, t8 = tid & 7;
            float s0 = 0.f, s1 = 0.f;
            #pragma unroll
            for (int j = 0; j < 8; ++j) {
                s0 += red[(row * 8 + j) * 16 + t8 * 2];
                s1 += red[(row * 8 + j) * 16 + t8 * 2 + 1];
            }
            size_t oo = ((size_t)nb * T_ + token0 + c * 64 + row) * 16 + t8 * 2;
            lpart[oo] = s0; lpart[oo + 1] = s1;
        }
    }
}

// ---------- K6: sum partials -> logits -> softmax -> top4 renorm -> alpha, entropy partials ----------
__global__ __launch_bounds__(256) void k6(const float* __restrict__ lpart,
        const float* __restrict__ rb2, float* __restrict__ alpha_out,
        float* __restrict__ entpart) {
    int blk = blockIdx.x;   // 1024
    int tid = threadIdx.x;
    int token = blk * 16 + (tid >> 4);
    int h = tid & 15;
    float lg = rb2[h];
    #pragma unroll
    for (int p = 0; p < 4; ++p) lg += lpart[((size_t)p * T_ + token) * 16 + h];

    float mx = lg;
    #pragma unroll
    for (int m = 1; m < 16; m <<= 1) mx = fmaxf(mx, __shfl_xor(mx, m));
    float e = expf(lg - mx);
    float sum = e;
    #pragma unroll
    for (int m = 1; m < 16; m <<= 1) sum += __shfl_xor(sum, m);
    float a0 = e / sum;

    float work = lg;
    bool sel = false;
    #pragma unroll
    for (int it = 0; it < 4; ++it) {
        float bv = work; int bi = h;
        #pragma unroll
        for (int m = 1; m < 16; m <<= 1) {
            float ov = __shfl_xor(bv, m); int oi = __shfl_xor(bi, m);
            if (ov > bv || (ov == bv && oi < bi)) { bv = ov; bi = oi; }
        }
        if (h == bi) { sel = true; work = -1e30f; }
    }
    float am = sel ? a0 : 0.f;
    float den = am;
    #pragma unroll
    for (int m = 1; m < 16; m <<= 1) den += __shfl_xor(den, m);
    den = fmaxf(den, 1e-12f);
    float a = am / den;
    alpha_out[(size_t)token * 16 + h] = a;

    float term = a * logf(fmaxf(a, 1e-12f));
    #pragma unroll
    for (int m = 1; m < 64; m <<= 1) term += __shfl_xor(term, m);
    __shared__ float tw[4];
    if ((tid & 63) == 0) tw[tid >> 6] = term;
    __syncthreads();
    if (tid == 0) entpart[blk] = tw[0] + tw[1] + tw[2] + tw[3];
}

// ---------- K7: entropy finalize ----------
__global__ __launch_bounds__(256) void k7(const float* __restrict__ entpart,
        float* __restrict__ out_ent) {
    int tid = threadIdx.x;
    float s = 0.f;
    for (int i = tid; i < 1024; i += 256) s += entpart[i];
    #pragma unroll
    for (int m = 1; m < 64; m <<= 1) s += __shfl_xor(s, m);
    __shared__ float tw[4];
    if ((tid & 63) == 0) tw[tid >> 6] = s;
    __syncthreads();
    if (tid == 0) out_ent[0] = -(tw[0] + tw[1] + tw[2] + tw[3]) * (1.f / (float)T_);
}

extern "C" void kernel_launch(void* const* d_in, const int* in_sizes, int n_in,
                              void* d_out, int out_size, void* d_ws, size_t ws_size,
                              hipStream_t stream) {
    const float* x     = (const float*)d_in[0];
    const float* state = (const float*)d_in[1];
    const float* pg    = (const float*)d_in[2];
    const float* pbv   = (const float*)d_in[3];
    const float* inpw  = (const float*)d_in[4];
    const float* inpb  = (const float*)d_in[5];
    const float* wzw   = (const float*)d_in[6];
    const float* wzb   = (const float*)d_in[7];
    const float* whw   = (const float*)d_in[8];
    const float* whb   = (const float*)d_in[9];
    const float* lnhg  = (const float*)d_in[10];
    const float* lnhb  = (const float*)d_in[11];
    const float* rlng  = (const float*)d_in[12];
    const float* rlnb  = (const float*)d_in[13];
    const float* rw1   = (const float*)d_in[14];
    const float* rb1   = (const float*)d_in[15];
    const float* rw2   = (const float*)d_in[16];
    const float* rb2   = (const float*)d_in[17];
    float* out = (float*)d_out;
    (void)in_sizes; (void)n_in; (void)out_size; (void)ws_size;

    char* base = (char*)d_ws;
    size_t off = 0;
    auto alloc = [&](size_t bytes) -> char* {
        char* p = base + off;
        off = (off + bytes + 255) & ~(size_t)255;
        return p;
    };
    u16*   xhi    = (u16*)alloc((size_t)T_ * D_ * 2);
    u16*   xlo    = (u16*)alloc((size_t)T_ * D_ * 2);
    u16*   whiT   = (u16*)alloc((size_t)D_ * D_ * 2);
    u16*   wloT   = (u16*)alloc((size_t)D_ * D_ * 2);
    float* c1part = (float*)alloc(32 * 1024 * 4);
    float* c2part = (float*)alloc(32 * 1024 * 4);
    float* sx     = (float*)alloc((size_t)T_ * 4);
    float* sxx    = (float*)alloc((size_t)T_ * 4);
    float* gpart  = (float*)alloc((size_t)8 * 32 * 1024 * 4);
    float* hnew   = (float*)alloc(8 * 1024 * 4);
    float* shb    = (float*)alloc(256);
    float* shhb   = (float*)alloc(256);
    float* lpart  = (float*)alloc((size_t)4 * T_ * H_ * 4);
    float* entpart= (float*)alloc(1024 * 4);
    float* partA  = (float*)alloc((size_t)32 * 8 * 1024 * 4);   // xctrl partials, then vmat partials
    float* partB  = (float*)alloc((size_t)32 * 8 * 1024 * 4);   // z partials
    float* partC  = (float*)alloc((size_t)32 * 8 * 1024 * 4);   // h partials

    k0a<<<dim3(16, 32), 256, 0, stream>>>(rw1, rlng, rlnb, whiT, wloT, c1part, c2part);
    k1<<<256, 256, 0, stream>>>(x, xhi, xlo, sx, sxx, gpart);
    kgemv_g<<<dim3(4, 32), 256, 0, stream>>>(gpart, pg, pbv, inpw, partA);
    kgemv2_f<<<dim3(4, 32), 256, 0, stream>>>(partA, inpb, wzw, whw, partB, partC);
    k3b_red_ln<<<8, 256, 0, stream>>>(partB, partC, wzb, whb, state, lnhg, lnhb,
                                      hnew, out + (size_t)T_ * H_, shb, shhb);
    kgemv_split<<<dim3(4, 32), 256, 0, stream>>>(hnew, rw1 + (size_t)1024 * 1024,
                                                 rlng + 1024, partA);
    k5_gemm<<<256, 512, 0, stream>>>(xhi, xlo, whiT, wloT, sx, sxx, shb, shhb,
                                     partA, c1part, c2part, rb1, rw2, lpart);
    k6<<<1024, 256, 0, stream>>>(lpart, rb2, out, entpart);
    k7<<<1, 256, 0, stream>>>(entpart, out + (size_t)T_ * H_ + (size_t)B_ * D_);
}

// Round 5
// 357.711 us; speedup vs baseline: 1.0020x; 1.0020x over previous
//
#include <hip/hip_runtime.h>
#include <hip/hip_bf16.h>
#include <math.h>

typedef unsigned short u16;
typedef __attribute__((ext_vector_type(8))) short bf16x8;
typedef __attribute__((ext_vector_type(4))) float f32x4;
typedef __attribute__((ext_vector_type(4))) unsigned short u16x4;

#define B_ 8
#define S_ 2048
#define T_ 16384
#define D_ 1024
#define H_ 16
#define EPS_ 1e-5f

__device__ __forceinline__ u16 f2bf(float f) {
    __hip_bfloat16 h = __float2bfloat16(f);
    union { __hip_bfloat16 h; u16 u; } cv; cv.h = h; return cv.u;
}
__device__ __forceinline__ float bf2f(u16 u) {
    union { u16 u; __hip_bfloat16 h; } cv; cv.u = u; return __bfloat162float(cv.h);
}

// ---------- K0a: W' = diag(rln_g[:1024])*r_w1[:1024] transposed + split bf16;
//            c1/c2 partials over all 2048 rows ----------
__global__ __launch_bounds__(256) void k0a(const float* __restrict__ rw1,
        const float* __restrict__ rlng, const float* __restrict__ rlnb,
        u16* __restrict__ whiT, u16* __restrict__ wloT,
        float* __restrict__ c1part, float* __restrict__ c2part) {
    int nb = blockIdx.x, kb = blockIdx.y;   // nb<16, kb<32
    int t = threadIdx.x;
    int nl = t & 63, kq = t >> 6;
    int n0 = nb * 64, k0 = kb * 64;
    __shared__ float ld[64][65];
    __shared__ float red[2][4][64];
    float a1 = 0.f, a2 = 0.f;
    #pragma unroll
    for (int r = 0; r < 16; ++r) {
        int kl = r * 4 + kq;
        int k = k0 + kl, n = n0 + nl;
        float w0 = rw1[(size_t)k * 1024 + n];
        ld[kl][nl] = w0;
        a1 += rlng[k] * w0;
        a2 += rlnb[k] * w0;
    }
    red[0][kq][nl] = a1;
    red[1][kq][nl] = a2;
    __syncthreads();
    if (t < 64) {
        c1part[(size_t)kb * 1024 + n0 + t] = red[0][0][t] + red[0][1][t] + red[0][2][t] + red[0][3][t];
        c2part[(size_t)kb * 1024 + n0 + t] = red[1][0][t] + red[1][1][t] + red[1][2][t] + red[1][3][t];
    }
    if (kb < 16) {
        #pragma unroll
        for (int r = 0; r < 16; ++r) {
            int nl2 = r * 4 + kq;
            int k = k0 + nl, n = n0 + nl2;
            float w0 = ld[nl][nl2] * rlng[k];
            u16 hi = f2bf(w0);
            float lo = w0 - bf2f(hi);
            whiT[(size_t)n * 1024 + k] = hi;
            wloT[(size_t)n * 1024 + k] = f2bf(lo);
        }
    }
}

// ---------- K1: pool LN pass over x; per-token sums; x -> split bf16 ----------
__global__ __launch_bounds__(256) void k1(const float* __restrict__ x,
        u16* __restrict__ xhi, u16* __restrict__ xlo,
        float* __restrict__ sx, float* __restrict__ sxx, float* __restrict__ gpart) {
    int blk = blockIdx.x;                  // 256 blocks
    int b = blk >> 5, chunk = blk & 31;
    int tid = threadIdx.x, w = tid >> 6, lane = tid & 63;
    __shared__ float lacc[4][1024];
    float acc[4][4];
    #pragma unroll
    for (int j = 0; j < 4; ++j)
        #pragma unroll
        for (int c = 0; c < 4; ++c) acc[j][c] = 0.f;

    for (int i = 0; i < 16; ++i) {
        int s = chunk * 64 + i * 4 + w;
        size_t tok = (size_t)b * S_ + s;
        size_t base = tok * D_;
        float4 v[4];
        float sum = 0.f, ssq = 0.f;
        #pragma unroll
        for (int j = 0; j < 4; ++j) {
            v[j] = *(const float4*)&x[base + j * 256 + lane * 4];
            sum += v[j].x + v[j].y + v[j].z + v[j].w;
            ssq += v[j].x * v[j].x + v[j].y * v[j].y + v[j].z * v[j].z + v[j].w * v[j].w;
        }
        #pragma unroll
        for (int m = 1; m < 64; m <<= 1) { sum += __shfl_xor(sum, m); ssq += __shfl_xor(ssq, m); }
        float mean = sum * (1.f / 1024.f);
        float var = ssq * (1.f / 1024.f) - mean * mean;
        float rstd = rsqrtf(var + EPS_);
        if (lane == 0) { sx[tok] = sum; sxx[tok] = ssq; }
        #pragma unroll
        for (int j = 0; j < 4; ++j) {
            float xs[4] = { v[j].x, v[j].y, v[j].z, v[j].w };
            u16 hs[4], ls[4];
            #pragma unroll
            for (int c = 0; c < 4; ++c) {
                acc[j][c] += (xs[c] - mean) * rstd;
                u16 h = f2bf(xs[c]);
                hs[c] = h;
                ls[c] = f2bf(xs[c] - bf2f(h));
            }
            size_t o = base + j * 256 + lane * 4;
            *(u16x4*)&xhi[o] = (u16x4){ hs[0], hs[1], hs[2], hs[3] };
            *(u16x4*)&xlo[o] = (u16x4){ ls[0], ls[1], ls[2], ls[3] };
        }
    }
    #pragma unroll
    for (int j = 0; j < 4; ++j)
        #pragma unroll
        for (int c = 0; c < 4; ++c) lacc[w][j * 256 + lane * 4 + c] = acc[j][c];
    __syncthreads();
    for (int q = 0; q < 4; ++q) {
        int n = q * 256 + tid;
        gpart[((size_t)b * 32 + chunk) * 1024 + n] =
            lacc[0][n] + lacc[1][n] + lacc[2][n] + lacc[3][n];
    }
}

// ---------- kgemv_g: fused g-vector build (reduce gpart) + split-K GEMV with inp_w ----------
__global__ __launch_bounds__(256) void kgemv_g(const float* __restrict__ gpart,
        const float* __restrict__ pg, const float* __restrict__ pb,
        const float* __restrict__ W, float* __restrict__ part) {
    int t = threadIdx.x;
    int n = blockIdx.x * 256 + t;
    int k0 = blockIdx.y * 32;
    __shared__ float sg[8][32];
    {
        int b = t >> 5, k = t & 31;
        float s = 0.f;
        #pragma unroll 8
        for (int p = 0; p < 32; ++p) s += gpart[((size_t)b * 32 + p) * 1024 + k0 + k];
        sg[b][k] = s * (1.f / 2048.f) * pg[k0 + k] + pb[k0 + k];
    }
    __syncthreads();
    float acc[8] = {};
    #pragma unroll
    for (int k = 0; k < 32; ++k) {
        float wv = W[(size_t)(k0 + k) * 1024 + n];
        #pragma unroll
        for (int b = 0; b < 8; ++b) acc[b] += sg[b][k] * wv;
    }
    #pragma unroll
    for (int b = 0; b < 8; ++b)
        part[((size_t)blockIdx.y * 8 + b) * 1024 + n] = acc[b];
}

// ---------- split-K GEMV: part[kb][b][n] = sum_{k in slice} in[b][k]*scale[k]*W[k][n] ----------
__global__ __launch_bounds__(256) void kgemv_split(const float* __restrict__ in,
        const float* __restrict__ W, const float* __restrict__ scale,
        float* __restrict__ part) {
    int t = threadIdx.x;
    int n = blockIdx.x * 256 + t;
    int k0 = blockIdx.y * 32;
    __shared__ float sg[8][32];
    {
        int b = t >> 5, k = t & 31;
        float v = in[b * 1024 + k0 + k];
        if (scale) v *= scale[k0 + k];
        sg[b][k] = v;
    }
    __syncthreads();
    float acc[8] = {};
    #pragma unroll
    for (int k = 0; k < 32; ++k) {
        float wv = W[(size_t)(k0 + k) * 1024 + n];
        #pragma unroll
        for (int b = 0; b < 8; ++b) acc[b] += sg[b][k] * wv;
    }
    #pragma unroll
    for (int b = 0; b < 8; ++b)
        part[((size_t)blockIdx.y * 8 + b) * 1024 + n] = acc[b];
}

// ---------- kgemv2_f: fused xctrl reduce(+bias) + dual split-K GEMV for W_z / W_h ----------
__global__ __launch_bounds__(256) void kgemv2_f(const float* __restrict__ partIn,
        const float* __restrict__ bias,
        const float* __restrict__ Wz, const float* __restrict__ Wh,
        float* __restrict__ zpart, float* __restrict__ hpart) {
    int t = threadIdx.x;
    int n = blockIdx.x * 256 + t;
    int k0 = blockIdx.y * 32;
    __shared__ float sg[8][32];
    {
        int b = t >> 5, k = t & 31;
        float s = bias[k0 + k];
        #pragma unroll 8
        for (int p = 0; p < 32; ++p) s += partIn[((size_t)p * 8 + b) * 1024 + k0 + k];
        sg[b][k] = s;
    }
    __syncthreads();
    float az[8] = {}, ah[8] = {};
    #pragma unroll
    for (int k = 0; k < 32; ++k) {
        size_t o = (size_t)(k0 + k) * 1024 + n;
        float wz = Wz[o];
        float wh = Wh[o];
        #pragma unroll
        for (int b = 0; b < 8; ++b) { az[b] += sg[b][k] * wz; ah[b] += sg[b][k] * wh; }
    }
    #pragma unroll
    for (int b = 0; b < 8; ++b) {
        size_t o = ((size_t)blockIdx.y * 8 + b) * 1024 + n;
        zpart[o] = az[b];
        hpart[o] = ah[b];
    }
}

// ---------- k3b reduce + gate + h-LayerNorm fused (grid 8, one block per b) ----------
__global__ __launch_bounds__(256) void k3b_red_ln(const float* __restrict__ zpart,
        const float* __restrict__ hpart, const float* __restrict__ bz,
        const float* __restrict__ bh, const float* __restrict__ state,
        const float* __restrict__ lg, const float* __restrict__ lb,
        float* __restrict__ hnew, float* __restrict__ outh,
        float* __restrict__ shb, float* __restrict__ shhb) {
    int b = blockIdx.x, tid = threadIdx.x;
    int w = tid >> 6, lane = tid & 63;
    __shared__ float rbuf[4][2];
    float hp[4];
    float sum = 0.f, ssq = 0.f;
    #pragma unroll
    for (int q = 0; q < 4; ++q) {
        int n = q * 256 + tid;
        float az = bz[n], ah = bh[n];
        #pragma unroll 8
        for (int p = 0; p < 32; ++p) {
            size_t o = ((size_t)p * 8 + b) * 1024 + n;
            az += zpart[o];
            ah += hpart[o];
        }
        float z = 1.f / (1.f + expf(-az));
        float hc = tanhf(ah);
        float v = (1.f - z) * state[(size_t)b * 1024 + n] + z * hc;
        hp[q] = v; sum += v; ssq += v * v;
    }
    #pragma unroll
    for (int m = 1; m < 64; m <<= 1) { sum += __shfl_xor(sum, m); ssq += __shfl_xor(ssq, m); }
    if (lane == 0) { rbuf[w][0] = sum; rbuf[w][1] = ssq; }
    __syncthreads();
    sum = rbuf[0][0] + rbuf[1][0] + rbuf[2][0] + rbuf[3][0];
    ssq = rbuf[0][1] + rbuf[1][1] + rbuf[2][1] + rbuf[3][1];
    float mean = sum * (1.f / 1024.f);
    float var = ssq * (1.f / 1024.f) - mean * mean;
    float rstd = rsqrtf(var + EPS_);
    float s2 = 0.f, q2 = 0.f;
    #pragma unroll
    for (int q = 0; q < 4; ++q) {
        int n = q * 256 + tid;
        float h = (hp[q] - mean) * rstd * lg[n] + lb[n];
        hnew[(size_t)b * 1024 + n] = h;
        outh[(size_t)b * 1024 + n] = h;
        s2 += h; q2 += h * h;
    }
    #pragma unroll
    for (int m = 1; m < 64; m <<= 1) { s2 += __shfl_xor(s2, m); q2 += __shfl_xor(q2, m); }
    __syncthreads();
    if (lane == 0) { rbuf[w][0] = s2; rbuf[w][1] = q2; }
    __syncthreads();
    if (tid == 0) {
        shb[b] = rbuf[0][0] + rbuf[1][0] + rbuf[2][0] + rbuf[3][0];
        shhb[b] = rbuf[0][1] + rbuf[1][1] + rbuf[2][1] + rbuf[3][1];
    }
}

// ---------- K5 v2: 8-phase 256x256 split-bf16 GEMM (flat K'=3072),
//   [256][64] swizzled tiles (conflict-free reads), stage-early + one vmcnt/tile ----------
__device__ __forceinline__ void gl16(const void* g, void* l) {
    __builtin_amdgcn_global_load_lds((const __attribute__((address_space(1))) void*)g,
                                     (__attribute__((address_space(3))) void*)l, 16, 0, 0);
}

// stage 2 chunks of A and 2 of B (chunks C0+tid, C0+512+tid) for tile kw into dbuf
// chunk ch: row=ch>>3, slot sl=ch&7 holds global k-slot s = sl ^ (row&7)  (involution)
#define STG2G(APL, BPL, C0, KW, DBUF) do { \
    if (t < 47) { \
        _Pragma("unroll") \
        for (int j_ = 0; j_ < 2; ++j_) { \
            int ch_ = (C0) + j_ * 512 + tid; \
            int row_ = ch_ >> 3; \
            int s_ = (ch_ & 7) ^ (row_ & 7); \
            gl16((APL) + aBase + (size_t)row_ * 1024 + (KW) + s_ * 8, \
                 smem + (DBUF) * 32768 + ch_ * 16); \
            gl16((BPL) + bBase + (size_t)row_ * 1024 + (KW) + s_ * 8, \
                 smem + 65536 + (DBUF) * 32768 + ch_ * 16); \
        } \
    } } while (0)

// phase: ds_read frags (swizzled slots) || stage, [vmcnt(0)], barrier, 16 MFMA, barrier
#define PHASE_V2(MH, KK, RDB, STG, WAIT0) do { \
    { const u16* pA_ = (const u16*)(smem + buf * 32768); \
      int sl_ = (((KK) * 4 + lq) ^ (l16 & 7)) * 8; \
      _Pragma("unroll") \
      for (int mi_ = 0; mi_ < 4; ++mi_) { \
          int row_ = wm * 128 + ((MH) * 4 + mi_) * 16 + l16; \
          fa[mi_] = *(const bf16x8*)&pA_[row_ * 64 + sl_]; \
      } \
      if (RDB) { const u16* pB_ = (const u16*)(smem + 65536 + buf * 32768); \
          _Pragma("unroll") \
          for (int ni_ = 0; ni_ < 4; ++ni_) { \
              int row_ = wn * 64 + ni_ * 16 + l16; \
              fb[(KK)][ni_] = *(const bf16x8*)&pB_[row_ * 64 + sl_]; \
          } } } \
    STG; \
    if (WAIT0) { asm volatile("s_waitcnt vmcnt(0)" ::: "memory"); } \
    __builtin_amdgcn_sched_barrier(0); \
    __builtin_amdgcn_s_barrier(); \
    __builtin_amdgcn_sched_barrier(0); \
    __builtin_amdgcn_s_setprio(1); \
    _Pragma("unroll") \
    for (int mi_ = 0; mi_ < 4; ++mi_) { \
        _Pragma("unroll") \
        for (int ni_ = 0; ni_ < 4; ++ni_) \
            acc[(MH) * 4 + mi_][ni_] = __builtin_amdgcn_mfma_f32_16x16x32_bf16( \
                fa[mi_], fb[(KK)][ni_], acc[(MH) * 4 + mi_][ni_], 0, 0, 0); \
    } \
    __builtin_amdgcn_s_setprio(0); \
    __builtin_amdgcn_sched_barrier(0); \
    __builtin_amdgcn_s_barrier(); \
    __builtin_amdgcn_sched_barrier(0); \
} while (0)

__global__ __launch_bounds__(512, 2) void k5_gemm(
        const u16* __restrict__ xhi, const u16* __restrict__ xlo,
        const u16* __restrict__ whiT, const u16* __restrict__ wloT,
        const float* __restrict__ sx, const float* __restrict__ sxx,
        const float* __restrict__ shb, const float* __restrict__ shhb,
        const float* __restrict__ vpart, const float* __restrict__ c1part,
        const float* __restrict__ c2part, const float* __restrict__ rb1,
        const float* __restrict__ rw2, float* __restrict__ lpart) {
    // LDS: A: 2 dbuf x [256][64] u16 = 64KB @0; B same @65536. Total 128KB.
    __shared__ unsigned char smem[131072];

    int bid = blockIdx.x;
    int o = (bid & 7) * 32 + (bid >> 3);   // XCD-bijective: 4 nb per mb share an XCD
    int nb = o & 3, mb = o >> 2;           // nb<4 (256 cols), mb<64 (256 tokens)
    int tid = threadIdx.x;
    int lane = tid & 63, wid = tid >> 6;
    int wm = wid >> 2, wn = wid & 3;       // 2M x 4N waves
    int l16 = lane & 15, lq = lane >> 4;

    f32x4 acc[8][4] = {};
    bf16x8 fa[4], fb[2][4];

    size_t aBase = (size_t)mb * 256 * 1024;
    size_t bBase = (size_t)nb * 256 * 1024;

    // prologue: stage tile 0 (xhi x whiT, kw=0) into buf 0
    #pragma unroll
    for (int j = 0; j < 4; ++j) {
        int ch = j * 512 + tid;
        int row = ch >> 3;
        int s = (ch & 7) ^ (row & 7);
        gl16(xhi + aBase + (size_t)row * 1024 + s * 8, smem + ch * 16);
        gl16(whiT + bBase + (size_t)row * 1024 + s * 8, smem + 65536 + ch * 16);
    }
    asm volatile("s_waitcnt vmcnt(0)" ::: "memory");
    __builtin_amdgcn_sched_barrier(0);
    __builtin_amdgcn_s_barrier();
    __builtin_amdgcn_sched_barrier(0);

    // K' = 3072: 48 tiles; seg: t<16 hi*hi, 16..31 hi*lo, 32..47 lo*hi
    for (int t = 0; t < 48; ++t) {
        int buf = t & 1;
        int tt = t + 1;
        const u16* Ap = (tt < 32) ? xhi : xlo;
        const u16* Bp = (tt >= 16 && tt < 32) ? wloT : whiT;
        size_t kw = (size_t)(tt & 15) * 64;
        PHASE_V2(0, 0, 1, STG2G(Ap, Bp, 0,    kw, buf ^ 1), 0);
        PHASE_V2(1, 0, 0, STG2G(Ap, Bp, 1024, kw, buf ^ 1), 0);
        PHASE_V2(0, 1, 1, ((void)0), 0);
        PHASE_V2(1, 1, 0, ((void)0), 1);
    }

    // ---- epilogue: 4 chunks x 64 rows through LDS ----
    int token0 = mb * 256;
    int bidx = mb >> 3;
    float vn[4], c1n[4], dn[4];
    #pragma unroll
    for (int nf = 0; nf < 4; ++nf) {
        int n = nb * 256 + wn * 64 + nf * 16 + l16;
        float sv = 0.f, s1 = 0.f, s2 = 0.f;
        for (int p = 0; p < 32; ++p) {
            sv += vpart[((size_t)p * 8 + bidx) * 1024 + n];
            s1 += c1part[(size_t)p * 1024 + n];
            s2 += c2part[(size_t)p * 1024 + n];
        }
        vn[nf] = sv; c1n[nf] = s1; dn[nf] = s2 + rb1[n];
    }
    float sH = shb[bidx], sHH = shhb[bidx];
    float* shid = (float*)smem;              // [64][260]
    float* red  = (float*)(smem + 66560);    // [64][8][16]

    #pragma unroll
    for (int c = 0; c < 4; ++c) {
        __syncthreads();
        if (wm == (c >> 1)) {
            #pragma unroll
            for (int mf2 = 0; mf2 < 4; ++mf2) {
                #pragma unroll
                for (int r = 0; r < 4; ++r) {
                    int rr = mf2 * 16 + lq * 4 + r;
                    int tok = token0 + c * 64 + rr;
                    float mean = (sx[tok] + sH) * (1.f / 2048.f);
                    float var = (sxx[tok] + sHH) * (1.f / 2048.f) - mean * mean;
                    float p = rsqrtf(var + EPS_);
                    float q = -mean * p;
                    #pragma unroll
                    for (int nf = 0; nf < 4; ++nf) {
                        int col = wn * 64 + nf * 16 + l16;
                        float pre = p * (acc[(c & 1) * 4 + mf2][nf][r] + vn[nf]) + q * c1n[nf] + dn[nf];
                        shid[rr * 260 + col] = 0.5f * pre * (1.f + erff(pre * 0.70710678118f));
                    }
                }
            }
        }
        __syncthreads();
        {   // partial logits over this block's 256 cols
            int row = tid >> 3, t8 = tid & 7;
            float a16[16];
            #pragma unroll
            for (int h = 0; h < 16; ++h) a16[h] = 0.f;
            #pragma unroll 4
            for (int cc = 0; cc < 32; ++cc) {
                int col = t8 * 32 + cc;
                float hv = shid[row * 260 + col];
                const float* w2p = rw2 + (size_t)(nb * 256 + col) * 16;
                float4 w0 = *(const float4*)(w2p);
                float4 w1 = *(const float4*)(w2p + 4);
                float4 w2 = *(const float4*)(w2p + 8);
                float4 w3 = *(const float4*)(w2p + 12);
                a16[0] += hv * w0.x; a16[1] += hv * w0.y; a16[2] += hv * w0.z; a16[3] += hv * w0.w;
                a16[4] += hv * w1.x; a16[5] += hv * w1.y; a16[6] += hv * w1.z; a16[7] += hv * w1.w;
                a16[8] += hv * w2.x; a16[9] += hv * w2.y; a16[10] += hv * w2.z; a16[11] += hv * w2.w;
                a16[12] += hv * w3.x; a16[13] += hv * w3.y; a16[14] += hv * w3.z; a16[15] += hv * w3.w;
            }
            #pragma unroll
            for (int h = 0; h < 16; ++h) red[(row * 8 + t8) * 16 + h] = a16[h];
        }
        __syncthreads();
        {
            int row = tid >> 3, t8 = tid & 7;
            float s0 = 0.f, s1 = 0.f;
            #pragma unroll
            for (int j = 0; j < 8; ++j) {
                s0 += red[(row * 8 + j) * 16 + t8 * 2];
                s1 += red[(row * 8 + j) * 16 + t8 * 2 + 1];
            }
            size_t oo = ((size_t)nb * T_ + token0 + c * 64 + row) * 16 + t8 * 2;
            lpart[oo] = s0; lpart[oo + 1] = s1;
        }
    }
}

// ---------- K6: sum partials -> logits -> softmax -> top4 renorm -> alpha, entropy partials ----------
__global__ __launch_bounds__(256) void k6(const float* __restrict__ lpart,
        const float* __restrict__ rb2, float* __restrict__ alpha_out,
        float* __restrict__ entpart) {
    int blk = blockIdx.x;   // 1024
    int tid = threadIdx.x;
    int token = blk * 16 + (tid >> 4);
    int h = tid & 15;
    float lg = rb2[h];
    #pragma unroll
    for (int p = 0; p < 4; ++p) lg += lpart[((size_t)p * T_ + token) * 16 + h];

    float mx = lg;
    #pragma unroll
    for (int m = 1; m < 16; m <<= 1) mx = fmaxf(mx, __shfl_xor(mx, m));
    float e = expf(lg - mx);
    float sum = e;
    #pragma unroll
    for (int m = 1; m < 16; m <<= 1) sum += __shfl_xor(sum, m);
    float a0 = e / sum;

    float work = lg;
    bool sel = false;
    #pragma unroll
    for (int it = 0; it < 4; ++it) {
        float bv = work; int bi = h;
        #pragma unroll
        for (int m = 1; m < 16; m <<= 1) {
            float ov = __shfl_xor(bv, m); int oi = __shfl_xor(bi, m);
            if (ov > bv || (ov == bv && oi < bi)) { bv = ov; bi = oi; }
        }
        if (h == bi) { sel = true; work = -1e30f; }
    }
    float am = sel ? a0 : 0.f;
    float den = am;
    #pragma unroll
    for (int m = 1; m < 16; m <<= 1) den += __shfl_xor(den, m);
    den = fmaxf(den, 1e-12f);
    float a = am / den;
    alpha_out[(size_t)token * 16 + h] = a;

    float term = a * logf(fmaxf(a, 1e-12f));
    #pragma unroll
    for (int m = 1; m < 64; m <<= 1) term += __shfl_xor(term, m);
    __shared__ float tw[4];
    if ((tid & 63) == 0) tw[tid >> 6] = term;
    __syncthreads();
    if (tid == 0) entpart[blk] = tw[0] + tw[1] + tw[2] + tw[3];
}

// ---------- K7: entropy finalize ----------
__global__ __launch_bounds__(256) void k7(const float* __restrict__ entpart,
        float* __restrict__ out_ent) {
    int tid = threadIdx.x;
    float s = 0.f;
    for (int i = tid; i < 1024; i += 256) s += entpart[i];
    #pragma unroll
    for (int m = 1; m < 64; m <<= 1) s += __shfl_xor(s, m);
    __shared__ float tw[4];
    if ((tid & 63) == 0) tw[tid >> 6] = s;
    __syncthreads();
    if (tid == 0) out_ent[0] = -(tw[0] + tw[1] + tw[2] + tw[3]) * (1.f / (float)T_);
}

extern "C" void kernel_launch(void* const* d_in, const int* in_sizes, int n_in,
                              void* d_out, int out_size, void* d_ws, size_t ws_size,
                              hipStream_t stream) {
    const float* x     = (const float*)d_in[0];
    const float* state = (const float*)d_in[1];
    const float* pg    = (const float*)d_in[2];
    const float* pbv   = (const float*)d_in[3];
    const float* inpw  = (const float*)d_in[4];
    const float* inpb  = (const float*)d_in[5];
    const float* wzw   = (const float*)d_in[6];
    const float* wzb   = (const float*)d_in[7];
    const float* whw   = (const float*)d_in[8];
    const float* whb   = (const float*)d_in[9];
    const float* lnhg  = (const float*)d_in[10];
    const float* lnhb  = (const float*)d_in[11];
    const float* rlng  = (const float*)d_in[12];
    const float* rlnb  = (const float*)d_in[13];
    const float* rw1   = (const float*)d_in[14];
    const float* rb1   = (const float*)d_in[15];
    const float* rw2   = (const float*)d_in[16];
    const float* rb2   = (const float*)d_in[17];
    float* out = (float*)d_out;
    (void)in_sizes; (void)n_in; (void)out_size; (void)ws_size;

    char* base = (char*)d_ws;
    size_t off = 0;
    auto alloc = [&](size_t bytes) -> char* {
        char* p = base + off;
        off = (off + bytes + 255) & ~(size_t)255;
        return p;
    };
    u16*   xhi    = (u16*)alloc((size_t)T_ * D_ * 2);
    u16*   xlo    = (u16*)alloc((size_t)T_ * D_ * 2);
    u16*   whiT   = (u16*)alloc((size_t)D_ * D_ * 2);
    u16*   wloT   = (u16*)alloc((size_t)D_ * D_ * 2);
    float* c1part = (float*)alloc(32 * 1024 * 4);
    float* c2part = (float*)alloc(32 * 1024 * 4);
    float* sx     = (float*)alloc((size_t)T_ * 4);
    float* sxx    = (float*)alloc((size_t)T_ * 4);
    float* gpart  = (float*)alloc((size_t)8 * 32 * 1024 * 4);
    float* hnew   = (float*)alloc(8 * 1024 * 4);
    float* shb    = (float*)alloc(256);
    float* shhb   = (float*)alloc(256);
    float* lpart  = (float*)alloc((size_t)4 * T_ * H_ * 4);
    float* entpart= (float*)alloc(1024 * 4);
    float* partA  = (float*)alloc((size_t)32 * 8 * 1024 * 4);   // xctrl partials, then vmat partials
    float* partB  = (float*)alloc((size_t)32 * 8 * 1024 * 4);   // z partials
    float* partC  = (float*)alloc((size_t)32 * 8 * 1024 * 4);   // h partials

    k0a<<<dim3(16, 32), 256, 0, stream>>>(rw1, rlng, rlnb, whiT, wloT, c1part, c2part);
    k1<<<256, 256, 0, stream>>>(x, xhi, xlo, sx, sxx, gpart);
    kgemv_g<<<dim3(4, 32), 256, 0, stream>>>(gpart, pg, pbv, inpw, partA);
    kgemv2_f<<<dim3(4, 32), 256, 0, stream>>>(partA, inpb, wzw, whw, partB, partC);
    k3b_red_ln<<<8, 256, 0, stream>>>(partB, partC, wzb, whb, state, lnhg, lnhb,
                                      hnew, out + (size_t)T_ * H_, shb, shhb);
    kgemv_split<<<dim3(4, 32), 256, 0, stream>>>(hnew, rw1 + (size_t)1024 * 1024,
                                                 rlng + 1024, partA);
    k5_gemm<<<256, 512, 0, stream>>>(xhi, xlo, whiT, wloT, sx, sxx, shb, shhb,
                                     partA, c1part, c2part, rb1, rw2, lpart);
    k6<<<1024, 256, 0, stream>>>(lpart, rb2, out, entpart);
    k7<<<1, 256, 0, stream>>>(entpart, out + (size_t)T_ * H_ + (size_t)B_ * D_);
}

// Round 6
// 301.920 us; speedup vs baseline: 1.1871x; 1.1848x over previous
//
#include <hip/hip_runtime.h>
#include <hip/hip_bf16.h>
#include <math.h>

typedef unsigned short u16;
typedef __attribute__((ext_vector_type(8))) short bf16x8;
typedef __attribute__((ext_vector_type(4))) float f32x4;
typedef __attribute__((ext_vector_type(4))) unsigned short u16x4;

#define B_ 8
#define S_ 2048
#define T_ 16384
#define D_ 1024
#define H_ 16
#define EPS_ 1e-5f

__device__ __forceinline__ u16 f2bf(float f) {
    __hip_bfloat16 h = __float2bfloat16(f);
    union { __hip_bfloat16 h; u16 u; } cv; cv.h = h; return cv.u;
}
__device__ __forceinline__ float bf2f(u16 u) {
    union { u16 u; __hip_bfloat16 h; } cv; cv.u = u; return __bfloat162float(cv.h);
}

// ---------- K0a: W' = diag(rln_g[:1024])*r_w1[:1024] transposed + split bf16;
//            c1/c2 partials over all 2048 rows ----------
__global__ __launch_bounds__(256) void k0a(const float* __restrict__ rw1,
        const float* __restrict__ rlng, const float* __restrict__ rlnb,
        u16* __restrict__ whiT, u16* __restrict__ wloT,
        float* __restrict__ c1part, float* __restrict__ c2part) {
    int nb = blockIdx.x, kb = blockIdx.y;   // nb<16, kb<32
    int t = threadIdx.x;
    int nl = t & 63, kq = t >> 6;
    int n0 = nb * 64, k0 = kb * 64;
    __shared__ float ld[64][65];
    __shared__ float red[2][4][64];
    float a1 = 0.f, a2 = 0.f;
    #pragma unroll
    for (int r = 0; r < 16; ++r) {
        int kl = r * 4 + kq;
        int k = k0 + kl, n = n0 + nl;
        float w0 = rw1[(size_t)k * 1024 + n];
        ld[kl][nl] = w0;
        a1 += rlng[k] * w0;
        a2 += rlnb[k] * w0;
    }
    red[0][kq][nl] = a1;
    red[1][kq][nl] = a2;
    __syncthreads();
    if (t < 64) {
        c1part[(size_t)kb * 1024 + n0 + t] = red[0][0][t] + red[0][1][t] + red[0][2][t] + red[0][3][t];
        c2part[(size_t)kb * 1024 + n0 + t] = red[1][0][t] + red[1][1][t] + red[1][2][t] + red[1][3][t];
    }
    if (kb < 16) {
        #pragma unroll
        for (int r = 0; r < 16; ++r) {
            int nl2 = r * 4 + kq;
            int k = k0 + nl, n = n0 + nl2;
            float w0 = ld[nl][nl2] * rlng[k];
            u16 hi = f2bf(w0);
            float lo = w0 - bf2f(hi);
            whiT[(size_t)n * 1024 + k] = hi;
            wloT[(size_t)n * 1024 + k] = f2bf(lo);
        }
    }
}

// ---------- K1: pool LN pass over x; per-token sums; x -> split bf16 ----------
__global__ __launch_bounds__(256) void k1(const float* __restrict__ x,
        u16* __restrict__ xhi, u16* __restrict__ xlo,
        float* __restrict__ sx, float* __restrict__ sxx, float* __restrict__ gpart) {
    int blk = blockIdx.x;                  // 256 blocks
    int b = blk >> 5, chunk = blk & 31;
    int tid = threadIdx.x, w = tid >> 6, lane = tid & 63;
    __shared__ float lacc[4][1024];
    float acc[4][4];
    #pragma unroll
    for (int j = 0; j < 4; ++j)
        #pragma unroll
        for (int c = 0; c < 4; ++c) acc[j][c] = 0.f;

    for (int i = 0; i < 16; ++i) {
        int s = chunk * 64 + i * 4 + w;
        size_t tok = (size_t)b * S_ + s;
        size_t base = tok * D_;
        float4 v[4];
        float sum = 0.f, ssq = 0.f;
        #pragma unroll
        for (int j = 0; j < 4; ++j) {
            v[j] = *(const float4*)&x[base + j * 256 + lane * 4];
            sum += v[j].x + v[j].y + v[j].z + v[j].w;
            ssq += v[j].x * v[j].x + v[j].y * v[j].y + v[j].z * v[j].z + v[j].w * v[j].w;
        }
        #pragma unroll
        for (int m = 1; m < 64; m <<= 1) { sum += __shfl_xor(sum, m); ssq += __shfl_xor(ssq, m); }
        float mean = sum * (1.f / 1024.f);
        float var = ssq * (1.f / 1024.f) - mean * mean;
        float rstd = rsqrtf(var + EPS_);
        if (lane == 0) { sx[tok] = sum; sxx[tok] = ssq; }
        #pragma unroll
        for (int j = 0; j < 4; ++j) {
            float xs[4] = { v[j].x, v[j].y, v[j].z, v[j].w };
            u16 hs[4], ls[4];
            #pragma unroll
            for (int c = 0; c < 4; ++c) {
                acc[j][c] += (xs[c] - mean) * rstd;
                u16 h = f2bf(xs[c]);
                hs[c] = h;
                ls[c] = f2bf(xs[c] - bf2f(h));
            }
            size_t o = base + j * 256 + lane * 4;
            *(u16x4*)&xhi[o] = (u16x4){ hs[0], hs[1], hs[2], hs[3] };
            *(u16x4*)&xlo[o] = (u16x4){ ls[0], ls[1], ls[2], ls[3] };
        }
    }
    #pragma unroll
    for (int j = 0; j < 4; ++j)
        #pragma unroll
        for (int c = 0; c < 4; ++c) lacc[w][j * 256 + lane * 4 + c] = acc[j][c];
    __syncthreads();
    for (int q = 0; q < 4; ++q) {
        int n = q * 256 + tid;
        gpart[((size_t)b * 32 + chunk) * 1024 + n] =
            lacc[0][n] + lacc[1][n] + lacc[2][n] + lacc[3][n];
    }
}

// ---------- kgemv_g: fused g-vector build (reduce gpart) + split-K GEMV with inp_w ----------
__global__ __launch_bounds__(256) void kgemv_g(const float* __restrict__ gpart,
        const float* __restrict__ pg, const float* __restrict__ pb,
        const float* __restrict__ W, float* __restrict__ part) {
    int t = threadIdx.x;
    int n = blockIdx.x * 256 + t;
    int k0 = blockIdx.y * 32;
    __shared__ float sg[8][32];
    {
        int b = t >> 5, k = t & 31;
        float s = 0.f;
        #pragma unroll 8
        for (int p = 0; p < 32; ++p) s += gpart[((size_t)b * 32 + p) * 1024 + k0 + k];
        sg[b][k] = s * (1.f / 2048.f) * pg[k0 + k] + pb[k0 + k];
    }
    __syncthreads();
    float acc[8] = {};
    #pragma unroll
    for (int k = 0; k < 32; ++k) {
        float wv = W[(size_t)(k0 + k) * 1024 + n];
        #pragma unroll
        for (int b = 0; b < 8; ++b) acc[b] += sg[b][k] * wv;
    }
    #pragma unroll
    for (int b = 0; b < 8; ++b)
        part[((size_t)blockIdx.y * 8 + b) * 1024 + n] = acc[b];
}

// ---------- split-K GEMV: part[kb][b][n] = sum_{k in slice} in[b][k]*scale[k]*W[k][n] ----------
__global__ __launch_bounds__(256) void kgemv_split(const float* __restrict__ in,
        const float* __restrict__ W, const float* __restrict__ scale,
        float* __restrict__ part) {
    int t = threadIdx.x;
    int n = blockIdx.x * 256 + t;
    int k0 = blockIdx.y * 32;
    __shared__ float sg[8][32];
    {
        int b = t >> 5, k = t & 31;
        float v = in[b * 1024 + k0 + k];
        if (scale) v *= scale[k0 + k];
        sg[b][k] = v;
    }
    __syncthreads();
    float acc[8] = {};
    #pragma unroll
    for (int k = 0; k < 32; ++k) {
        float wv = W[(size_t)(k0 + k) * 1024 + n];
        #pragma unroll
        for (int b = 0; b < 8; ++b) acc[b] += sg[b][k] * wv;
    }
    #pragma unroll
    for (int b = 0; b < 8; ++b)
        part[((size_t)blockIdx.y * 8 + b) * 1024 + n] = acc[b];
}

// ---------- kgemv2_f: fused xctrl reduce(+bias) + dual split-K GEMV for W_z / W_h ----------
__global__ __launch_bounds__(256) void kgemv2_f(const float* __restrict__ partIn,
        const float* __restrict__ bias,
        const float* __restrict__ Wz, const float* __restrict__ Wh,
        float* __restrict__ zpart, float* __restrict__ hpart) {
    int t = threadIdx.x;
    int n = blockIdx.x * 256 + t;
    int k0 = blockIdx.y * 32;
    __shared__ float sg[8][32];
    {
        int b = t >> 5, k = t & 31;
        float s = bias[k0 + k];
        #pragma unroll 8
        for (int p = 0; p < 32; ++p) s += partIn[((size_t)p * 8 + b) * 1024 + k0 + k];
        sg[b][k] = s;
    }
    __syncthreads();
    float az[8] = {}, ah[8] = {};
    #pragma unroll
    for (int k = 0; k < 32; ++k) {
        size_t o = (size_t)(k0 + k) * 1024 + n;
        float wz = Wz[o];
        float wh = Wh[o];
        #pragma unroll
        for (int b = 0; b < 8; ++b) { az[b] += sg[b][k] * wz; ah[b] += sg[b][k] * wh; }
    }
    #pragma unroll
    for (int b = 0; b < 8; ++b) {
        size_t o = ((size_t)blockIdx.y * 8 + b) * 1024 + n;
        zpart[o] = az[b];
        hpart[o] = ah[b];
    }
}

// ---------- k3b reduce + gate + h-LayerNorm fused (grid 8, one block per b) ----------
__global__ __launch_bounds__(256) void k3b_red_ln(const float* __restrict__ zpart,
        const float* __restrict__ hpart, const float* __restrict__ bz,
        const float* __restrict__ bh, const float* __restrict__ state,
        const float* __restrict__ lg, const float* __restrict__ lb,
        float* __restrict__ hnew, float* __restrict__ outh,
        float* __restrict__ shb, float* __restrict__ shhb) {
    int b = blockIdx.x, tid = threadIdx.x;
    int w = tid >> 6, lane = tid & 63;
    __shared__ float rbuf[4][2];
    float hp[4];
    float sum = 0.f, ssq = 0.f;
    #pragma unroll
    for (int q = 0; q < 4; ++q) {
        int n = q * 256 + tid;
        float az = bz[n], ah = bh[n];
        #pragma unroll 8
        for (int p = 0; p < 32; ++p) {
            size_t o = ((size_t)p * 8 + b) * 1024 + n;
            az += zpart[o];
            ah += hpart[o];
        }
        float z = 1.f / (1.f + expf(-az));
        float hc = tanhf(ah);
        float v = (1.f - z) * state[(size_t)b * 1024 + n] + z * hc;
        hp[q] = v; sum += v; ssq += v * v;
    }
    #pragma unroll
    for (int m = 1; m < 64; m <<= 1) { sum += __shfl_xor(sum, m); ssq += __shfl_xor(ssq, m); }
    if (lane == 0) { rbuf[w][0] = sum; rbuf[w][1] = ssq; }
    __syncthreads();
    sum = rbuf[0][0] + rbuf[1][0] + rbuf[2][0] + rbuf[3][0];
    ssq = rbuf[0][1] + rbuf[1][1] + rbuf[2][1] + rbuf[3][1];
    float mean = sum * (1.f / 1024.f);
    float var = ssq * (1.f / 1024.f) - mean * mean;
    float rstd = rsqrtf(var + EPS_);
    float s2 = 0.f, q2 = 0.f;
    #pragma unroll
    for (int q = 0; q < 4; ++q) {
        int n = q * 256 + tid;
        float h = (hp[q] - mean) * rstd * lg[n] + lb[n];
        hnew[(size_t)b * 1024 + n] = h;
        outh[(size_t)b * 1024 + n] = h;
        s2 += h; q2 += h * h;
    }
    #pragma unroll
    for (int m = 1; m < 64; m <<= 1) { s2 += __shfl_xor(s2, m); q2 += __shfl_xor(q2, m); }
    __syncthreads();
    if (lane == 0) { rbuf[w][0] = s2; rbuf[w][1] = q2; }
    __syncthreads();
    if (tid == 0) {
        shb[b] = rbuf[0][0] + rbuf[1][0] + rbuf[2][0] + rbuf[3][0];
        shhb[b] = rbuf[0][1] + rbuf[1][1] + rbuf[2][1] + rbuf[3][1];
    }
}

// ---------- K5 (round-1 known-good structure + slot-swizzle + fused epilogue):
//   split-bf16 MFMA GEMM u = x @ W', 128x128 tile, BK=64, 2-barrier K-loop ----------
__device__ __forceinline__ void gl16(const void* g, void* l) {
    __builtin_amdgcn_global_load_lds((const __attribute__((address_space(1))) void*)g,
                                     (__attribute__((address_space(3))) void*)l, 16, 0, 0);
}

__global__ __launch_bounds__(256, 1) void k5_gemm(
        const u16* __restrict__ xhi, const u16* __restrict__ xlo,
        const u16* __restrict__ whiT, const u16* __restrict__ wloT,
        const float* __restrict__ sx, const float* __restrict__ sxx,
        const float* __restrict__ shb, const float* __restrict__ shhb,
        const float* __restrict__ vpart, const float* __restrict__ c1part,
        const float* __restrict__ c2part, const float* __restrict__ rb1,
        const float* __restrict__ rw2, float* __restrict__ lpart) {
    __shared__ unsigned char smem[66048];
    u16* sAh = (u16*)smem;
    u16* sAl = sAh + 128 * 64;
    u16* sBh = sAl + 128 * 64;
    u16* sBl = sBh + 128 * 64;
    float* shid = (float*)smem;   // reused after main loop: [128][129]

    int nb = blockIdx.x, mb = blockIdx.y;   // (8, 128)
    int tid = threadIdx.x;
    int lane = tid & 63, wid = tid >> 6;
    int wm = wid >> 1, wn = wid & 1;
    int l16 = lane & 15, lq = lane >> 4;

    f32x4 acc[4][4] = {};

    size_t aBase = (size_t)mb * 128 * 1024;
    size_t bBase = (size_t)nb * 128 * 1024;

    for (int kb = 0; kb < 16; ++kb) {
        __syncthreads();
        #pragma unroll
        for (int i = 0; i < 4; ++i) {
            int chunk = tid + 256 * i;
            int row = chunk >> 3, c8 = chunk & 7;
            int s8 = c8 ^ (row & 7);            // involution slot-swizzle (16B granules)
            size_t go = (size_t)row * 1024 + (size_t)kb * 64 + s8 * 8;
            int lo = chunk * 16;                // linear LDS dest (gl16 constraint)
            gl16(xhi + aBase + go, (char*)sAh + lo);
            gl16(xlo + aBase + go, (char*)sAl + lo);
            gl16(whiT + bBase + go, (char*)sBh + lo);
            gl16(wloT + bBase + go, (char*)sBl + lo);
        }
        asm volatile("s_waitcnt vmcnt(0)" ::: "memory");
        __syncthreads();
        #pragma unroll
        for (int kk = 0; kk < 2; ++kk) {
            bf16x8 ah[4], al[4], bh[4], bl[4];
            // swizzled read slot: rows within a frag differ only in l16; row&7 == l16&7
            int sl = ((kk * 4 + lq) ^ (l16 & 7)) * 8;
            #pragma unroll
            for (int f = 0; f < 4; ++f) {
                int ar = wm * 64 + f * 16 + l16;
                int br = wn * 64 + f * 16 + l16;
                ah[f] = *(const bf16x8*)&sAh[ar * 64 + sl];
                al[f] = *(const bf16x8*)&sAl[ar * 64 + sl];
                bh[f] = *(const bf16x8*)&sBh[br * 64 + sl];
                bl[f] = *(const bf16x8*)&sBl[br * 64 + sl];
            }
            #pragma unroll
            for (int mf = 0; mf < 4; ++mf)
                #pragma unroll
                for (int nf = 0; nf < 4; ++nf) {
                    acc[mf][nf] = __builtin_amdgcn_mfma_f32_16x16x32_bf16(ah[mf], bh[nf], acc[mf][nf], 0, 0, 0);
                    acc[mf][nf] = __builtin_amdgcn_mfma_f32_16x16x32_bf16(ah[mf], bl[nf], acc[mf][nf], 0, 0, 0);
                    acc[mf][nf] = __builtin_amdgcn_mfma_f32_16x16x32_bf16(al[mf], bh[nf], acc[mf][nf], 0, 0, 0);
                }
        }
    }
    __syncthreads();

    // ---- fused epilogue: per-col constants (reduce vpart/c1part/c2part) ----
    int token0 = mb * 128;
    int bidx = mb >> 4;
    float vn[4], c1n[4], dn[4];
    #pragma unroll
    for (int nf = 0; nf < 4; ++nf) {
        int n = nb * 128 + wn * 64 + nf * 16 + l16;
        float sv = 0.f, s1 = 0.f, s2 = 0.f;
        for (int p = 0; p < 32; ++p) {
            sv += vpart[((size_t)p * 8 + bidx) * 1024 + n];
            s1 += c1part[(size_t)p * 1024 + n];
            s2 += c2part[(size_t)p * 1024 + n];
        }
        vn[nf] = sv; c1n[nf] = s1; dn[nf] = s2 + rb1[n];
    }
    float sH = shb[bidx], sHH = shhb[bidx];

    // hid = gelu(p*(u+v) + q*c1 + d) -> LDS
    #pragma unroll
    for (int mf = 0; mf < 4; ++mf) {
        #pragma unroll
        for (int r = 0; r < 4; ++r) {
            int rowl = wm * 64 + mf * 16 + lq * 4 + r;
            int tok = token0 + rowl;
            float mean = (sx[tok] + sH) * (1.f / 2048.f);
            float var = (sxx[tok] + sHH) * (1.f / 2048.f) - mean * mean;
            float p = rsqrtf(var + EPS_);
            float q = -mean * p;
            #pragma unroll
            for (int nf = 0; nf < 4; ++nf) {
                int coll = wn * 64 + nf * 16 + l16;
                float pre = p * (acc[mf][nf][r] + vn[nf]) + q * c1n[nf] + dn[nf];
                float hid = 0.5f * pre * (1.f + erff(pre * 0.70710678118f));
                shid[rowl * 129 + coll] = hid;
            }
        }
    }
    __syncthreads();

    // partial logits for this N-block: [128 tokens][16 heads]
    int r2 = tid >> 1, half = tid & 1;
    const float* w2b = rw2 + (size_t)nb * 128 * 16 + half * 8;
    float a8[8];
    #pragma unroll
    for (int h = 0; h < 8; ++h) a8[h] = 0.f;
    #pragma unroll 8
    for (int j = 0; j < 128; ++j) {
        float hv = shid[r2 * 129 + j];
        float4 w0 = *(const float4*)(w2b + (size_t)j * 16);
        float4 w1 = *(const float4*)(w2b + (size_t)j * 16 + 4);
        a8[0] += hv * w0.x; a8[1] += hv * w0.y; a8[2] += hv * w0.z; a8[3] += hv * w0.w;
        a8[4] += hv * w1.x; a8[5] += hv * w1.y; a8[6] += hv * w1.z; a8[7] += hv * w1.w;
    }
    float* lp = lpart + ((size_t)nb * T_ + token0 + r2) * 16 + half * 8;
    #pragma unroll
    for (int h = 0; h < 8; ++h) lp[h] = a8[h];
}

// ---------- K6: sum partials -> logits -> softmax -> top4 renorm -> alpha, entropy partials ----------
__global__ __launch_bounds__(256) void k6(const float* __restrict__ lpart,
        const float* __restrict__ rb2, float* __restrict__ alpha_out,
        float* __restrict__ entpart) {
    int blk = blockIdx.x;   // 1024
    int tid = threadIdx.x;
    int token = blk * 16 + (tid >> 4);
    int h = tid & 15;
    float lg = rb2[h];
    #pragma unroll
    for (int p = 0; p < 8; ++p) lg += lpart[((size_t)p * T_ + token) * 16 + h];

    float mx = lg;
    #pragma unroll
    for (int m = 1; m < 16; m <<= 1) mx = fmaxf(mx, __shfl_xor(mx, m));
    float e = expf(lg - mx);
    float sum = e;
    #pragma unroll
    for (int m = 1; m < 16; m <<= 1) sum += __shfl_xor(sum, m);
    float a0 = e / sum;

    float work = lg;
    bool sel = false;
    #pragma unroll
    for (int it = 0; it < 4; ++it) {
        float bv = work; int bi = h;
        #pragma unroll
        for (int m = 1; m < 16; m <<= 1) {
            float ov = __shfl_xor(bv, m); int oi = __shfl_xor(bi, m);
            if (ov > bv || (ov == bv && oi < bi)) { bv = ov; bi = oi; }
        }
        if (h == bi) { sel = true; work = -1e30f; }
    }
    float am = sel ? a0 : 0.f;
    float den = am;
    #pragma unroll
    for (int m = 1; m < 16; m <<= 1) den += __shfl_xor(den, m);
    den = fmaxf(den, 1e-12f);
    float a = am / den;
    alpha_out[(size_t)token * 16 + h] = a;

    float term = a * logf(fmaxf(a, 1e-12f));
    #pragma unroll
    for (int m = 1; m < 64; m <<= 1) term += __shfl_xor(term, m);
    __shared__ float tw[4];
    if ((tid & 63) == 0) tw[tid >> 6] = term;
    __syncthreads();
    if (tid == 0) entpart[blk] = tw[0] + tw[1] + tw[2] + tw[3];
}

// ---------- K7: entropy finalize ----------
__global__ __launch_bounds__(256) void k7(const float* __restrict__ entpart,
        float* __restrict__ out_ent) {
    int tid = threadIdx.x;
    float s = 0.f;
    for (int i = tid; i < 1024; i += 256) s += entpart[i];
    #pragma unroll
    for (int m = 1; m < 64; m <<= 1) s += __shfl_xor(s, m);
    __shared__ float tw[4];
    if ((tid & 63) == 0) tw[tid >> 6] = s;
    __syncthreads();
    if (tid == 0) out_ent[0] = -(tw[0] + tw[1] + tw[2] + tw[3]) * (1.f / (float)T_);
}

extern "C" void kernel_launch(void* const* d_in, const int* in_sizes, int n_in,
                              void* d_out, int out_size, void* d_ws, size_t ws_size,
                              hipStream_t stream) {
    const float* x     = (const float*)d_in[0];
    const float* state = (const float*)d_in[1];
    const float* pg    = (const float*)d_in[2];
    const float* pbv   = (const float*)d_in[3];
    const float* inpw  = (const float*)d_in[4];
    const float* inpb  = (const float*)d_in[5];
    const float* wzw   = (const float*)d_in[6];
    const float* wzb   = (const float*)d_in[7];
    const float* whw   = (const float*)d_in[8];
    const float* whb   = (const float*)d_in[9];
    const float* lnhg  = (const float*)d_in[10];
    const float* lnhb  = (const float*)d_in[11];
    const float* rlng  = (const float*)d_in[12];
    const float* rlnb  = (const float*)d_in[13];
    const float* rw1   = (const float*)d_in[14];
    const float* rb1   = (const float*)d_in[15];
    const float* rw2   = (const float*)d_in[16];
    const float* rb2   = (const float*)d_in[17];
    float* out = (float*)d_out;
    (void)in_sizes; (void)n_in; (void)out_size; (void)ws_size;

    char* base = (char*)d_ws;
    size_t off = 0;
    auto alloc = [&](size_t bytes) -> char* {
        char* p = base + off;
        off = (off + bytes + 255) & ~(size_t)255;
        return p;
    };
    u16*   xhi    = (u16*)alloc((size_t)T_ * D_ * 2);
    u16*   xlo    = (u16*)alloc((size_t)T_ * D_ * 2);
    u16*   whiT   = (u16*)alloc((size_t)D_ * D_ * 2);
    u16*   wloT   = (u16*)alloc((size_t)D_ * D_ * 2);
    float* c1part = (float*)alloc(32 * 1024 * 4);
    float* c2part = (float*)alloc(32 * 1024 * 4);
    float* sx     = (float*)alloc((size_t)T_ * 4);
    float* sxx    = (float*)alloc((size_t)T_ * 4);
    float* gpart  = (float*)alloc((size_t)8 * 32 * 1024 * 4);
    float* hnew   = (float*)alloc(8 * 1024 * 4);
    float* shb    = (float*)alloc(256);
    float* shhb   = (float*)alloc(256);
    float* lpart  = (float*)alloc((size_t)8 * T_ * H_ * 4);
    float* entpart= (float*)alloc(1024 * 4);
    float* partA  = (float*)alloc((size_t)32 * 8 * 1024 * 4);   // xctrl partials, then vmat partials
    float* partB  = (float*)alloc((size_t)32 * 8 * 1024 * 4);   // z partials
    float* partC  = (float*)alloc((size_t)32 * 8 * 1024 * 4);   // h partials

    k0a<<<dim3(16, 32), 256, 0, stream>>>(rw1, rlng, rlnb, whiT, wloT, c1part, c2part);
    k1<<<256, 256, 0, stream>>>(x, xhi, xlo, sx, sxx, gpart);
    kgemv_g<<<dim3(4, 32), 256, 0, stream>>>(gpart, pg, pbv, inpw, partA);
    kgemv2_f<<<dim3(4, 32), 256, 0, stream>>>(partA, inpb, wzw, whw, partB, partC);
    k3b_red_ln<<<8, 256, 0, stream>>>(partB, partC, wzb, whb, state, lnhg, lnhb,
                                      hnew, out + (size_t)T_ * H_, shb, shhb);
    kgemv_split<<<dim3(4, 32), 256, 0, stream>>>(hnew, rw1 + (size_t)1024 * 1024,
                                                 rlng + 1024, partA);
    k5_gemm<<<dim3(8, 128), 256, 0, stream>>>(xhi, xlo, whiT, wloT, sx, sxx, shb, shhb,
                                              partA, c1part, c2part, rb1, rw2, lpart);
    k6<<<1024, 256, 0, stream>>>(lpart, rb2, out, entpart);
    k7<<<1, 256, 0, stream>>>(entpart, out + (size_t)T_ * H_ + (size_t)B_ * D_);
}

// Round 7
// 228.337 us; speedup vs baseline: 1.5697x; 1.3223x over previous
//
#include <hip/hip_runtime.h>
#include <hip/hip_bf16.h>
#include <math.h>

typedef unsigned short u16;
typedef __attribute__((ext_vector_type(8))) short bf16x8;
typedef __attribute__((ext_vector_type(4))) float f32x4;
typedef __attribute__((ext_vector_type(4))) unsigned short u16x4;

#define B_ 8
#define S_ 2048
#define T_ 16384
#define D_ 1024
#define H_ 16
#define EPS_ 1e-5f

__device__ __forceinline__ u16 f2bf(float f) {
    __hip_bfloat16 h = __float2bfloat16(f);
    union { __hip_bfloat16 h; u16 u; } cv; cv.h = h; return cv.u;
}
__device__ __forceinline__ float bf2f(u16 u) {
    union { u16 u; __hip_bfloat16 h; } cv; cv.u = u; return __bfloat162float(cv.h);
}

// ---------- K0a: W' = diag(rln_g[:1024])*r_w1[:1024] transposed + split bf16;
//            c1/c2 partials over all 2048 rows ----------
__global__ __launch_bounds__(256) void k0a(const float* __restrict__ rw1,
        const float* __restrict__ rlng, const float* __restrict__ rlnb,
        u16* __restrict__ whiT, u16* __restrict__ wloT,
        float* __restrict__ c1part, float* __restrict__ c2part) {
    int nb = blockIdx.x, kb = blockIdx.y;   // nb<16, kb<32
    int t = threadIdx.x;
    int nl = t & 63, kq = t >> 6;
    int n0 = nb * 64, k0 = kb * 64;
    __shared__ float ld[64][65];
    __shared__ float red[2][4][64];
    float a1 = 0.f, a2 = 0.f;
    #pragma unroll
    for (int r = 0; r < 16; ++r) {
        int kl = r * 4 + kq;
        int k = k0 + kl, n = n0 + nl;
        float w0 = rw1[(size_t)k * 1024 + n];
        ld[kl][nl] = w0;
        a1 += rlng[k] * w0;
        a2 += rlnb[k] * w0;
    }
    red[0][kq][nl] = a1;
    red[1][kq][nl] = a2;
    __syncthreads();
    if (t < 64) {
        c1part[(size_t)kb * 1024 + n0 + t] = red[0][0][t] + red[0][1][t] + red[0][2][t] + red[0][3][t];
        c2part[(size_t)kb * 1024 + n0 + t] = red[1][0][t] + red[1][1][t] + red[1][2][t] + red[1][3][t];
    }
    if (kb < 16) {
        #pragma unroll
        for (int r = 0; r < 16; ++r) {
            int nl2 = r * 4 + kq;
            int k = k0 + nl, n = n0 + nl2;
            float w0 = ld[nl][nl2] * rlng[k];
            u16 hi = f2bf(w0);
            float lo = w0 - bf2f(hi);
            whiT[(size_t)n * 1024 + k] = hi;
            wloT[(size_t)n * 1024 + k] = f2bf(lo);
        }
    }
}

// ---------- K0b: reduce c1/c2 partials; dvec = c2 + r_b1 ----------
__global__ __launch_bounds__(256) void k0b(const float* __restrict__ c1part,
        const float* __restrict__ c2part, const float* __restrict__ rb1,
        float* __restrict__ c1, float* __restrict__ dvec) {
    int n = blockIdx.x * 256 + threadIdx.x;   // grid 4
    float s1 = 0.f, s2 = 0.f;
    for (int p = 0; p < 32; ++p) { s1 += c1part[p * 1024 + n]; s2 += c2part[p * 1024 + n]; }
    c1[n] = s1;
    dvec[n] = s2 + rb1[n];
}

// ---------- K1: pool LN pass over x; per-token sums; x -> split bf16 ----------
__global__ __launch_bounds__(256) void k1(const float* __restrict__ x,
        u16* __restrict__ xhi, u16* __restrict__ xlo,
        float* __restrict__ sx, float* __restrict__ sxx, float* __restrict__ gpart) {
    int blk = blockIdx.x;                  // 256 blocks
    int b = blk >> 5, chunk = blk & 31;
    int tid = threadIdx.x, w = tid >> 6, lane = tid & 63;
    __shared__ float lacc[4][1024];
    float acc[4][4];
    #pragma unroll
    for (int j = 0; j < 4; ++j)
        #pragma unroll
        for (int c = 0; c < 4; ++c) acc[j][c] = 0.f;

    for (int i = 0; i < 16; ++i) {
        int s = chunk * 64 + i * 4 + w;
        size_t tok = (size_t)b * S_ + s;
        size_t base = tok * D_;
        float4 v[4];
        float sum = 0.f, ssq = 0.f;
        #pragma unroll
        for (int j = 0; j < 4; ++j) {
            v[j] = *(const float4*)&x[base + j * 256 + lane * 4];
            sum += v[j].x + v[j].y + v[j].z + v[j].w;
            ssq += v[j].x * v[j].x + v[j].y * v[j].y + v[j].z * v[j].z + v[j].w * v[j].w;
        }
        #pragma unroll
        for (int m = 1; m < 64; m <<= 1) { sum += __shfl_xor(sum, m); ssq += __shfl_xor(ssq, m); }
        float mean = sum * (1.f / 1024.f);
        float var = ssq * (1.f / 1024.f) - mean * mean;
        float rstd = rsqrtf(var + EPS_);
        if (lane == 0) { sx[tok] = sum; sxx[tok] = ssq; }
        #pragma unroll
        for (int j = 0; j < 4; ++j) {
            float xs[4] = { v[j].x, v[j].y, v[j].z, v[j].w };
            u16 hs[4], ls[4];
            #pragma unroll
            for (int c = 0; c < 4; ++c) {
                acc[j][c] += (xs[c] - mean) * rstd;
                u16 h = f2bf(xs[c]);
                hs[c] = h;
                ls[c] = f2bf(xs[c] - bf2f(h));
            }
            size_t o = base + j * 256 + lane * 4;
            *(u16x4*)&xhi[o] = (u16x4){ hs[0], hs[1], hs[2], hs[3] };
            *(u16x4*)&xlo[o] = (u16x4){ ls[0], ls[1], ls[2], ls[3] };
        }
    }
    #pragma unroll
    for (int j = 0; j < 4; ++j)
        #pragma unroll
        for (int c = 0; c < 4; ++c) lacc[w][j * 256 + lane * 4 + c] = acc[j][c];
    __syncthreads();
    for (int q = 0; q < 4; ++q) {
        int n = q * 256 + tid;
        gpart[((size_t)b * 32 + chunk) * 1024 + n] =
            lacc[0][n] + lacc[1][n] + lacc[2][n] + lacc[3][n];
    }
}

// ---------- kgemv_g: fused g-vector build (reduce gpart) + split-K GEMV with inp_w ----------
__global__ __launch_bounds__(256) void kgemv_g(const float* __restrict__ gpart,
        const float* __restrict__ pg, const float* __restrict__ pb,
        const float* __restrict__ W, float* __restrict__ part) {
    int t = threadIdx.x;
    int n = blockIdx.x * 256 + t;
    int k0 = blockIdx.y * 32;
    __shared__ float sg[8][32];
    {
        int b = t >> 5, k = t & 31;
        float s = 0.f;
        #pragma unroll 8
        for (int p = 0; p < 32; ++p) s += gpart[((size_t)b * 32 + p) * 1024 + k0 + k];
        sg[b][k] = s * (1.f / 2048.f) * pg[k0 + k] + pb[k0 + k];
    }
    __syncthreads();
    float acc[8] = {};
    #pragma unroll
    for (int k = 0; k < 32; ++k) {
        float wv = W[(size_t)(k0 + k) * 1024 + n];
        #pragma unroll
        for (int b = 0; b < 8; ++b) acc[b] += sg[b][k] * wv;
    }
    #pragma unroll
    for (int b = 0; b < 8; ++b)
        part[((size_t)blockIdx.y * 8 + b) * 1024 + n] = acc[b];
}

// ---------- split-K GEMV: part[kb][b][n] = sum_{k in slice} in[b][k]*scale[k]*W[k][n] ----------
__global__ __launch_bounds__(256) void kgemv_split(const float* __restrict__ in,
        const float* __restrict__ W, const float* __restrict__ scale,
        float* __restrict__ part) {
    int t = threadIdx.x;
    int n = blockIdx.x * 256 + t;
    int k0 = blockIdx.y * 32;
    __shared__ float sg[8][32];
    {
        int b = t >> 5, k = t & 31;
        float v = in[b * 1024 + k0 + k];
        if (scale) v *= scale[k0 + k];
        sg[b][k] = v;
    }
    __syncthreads();
    float acc[8] = {};
    #pragma unroll
    for (int k = 0; k < 32; ++k) {
        float wv = W[(size_t)(k0 + k) * 1024 + n];
        #pragma unroll
        for (int b = 0; b < 8; ++b) acc[b] += sg[b][k] * wv;
    }
    #pragma unroll
    for (int b = 0; b < 8; ++b)
        part[((size_t)blockIdx.y * 8 + b) * 1024 + n] = acc[b];
}

// ---------- reduce 32 partials + bias -> out  (grid 32) ----------
__global__ __launch_bounds__(256) void kred_bias(const float* __restrict__ part,
        const float* __restrict__ bias, float* __restrict__ out) {
    int i = blockIdx.x * 256 + threadIdx.x;
    int b = i >> 10, n = i & 1023;
    float s = bias ? bias[n] : 0.f;
    #pragma unroll 8
    for (int p = 0; p < 32; ++p) s += part[((size_t)p * 8 + b) * 1024 + n];
    out[i] = s;
}

// ---------- kgemv2_f: fused xctrl reduce(+bias) + dual split-K GEMV for W_z / W_h ----------
__global__ __launch_bounds__(256) void kgemv2_f(const float* __restrict__ partIn,
        const float* __restrict__ bias,
        const float* __restrict__ Wz, const float* __restrict__ Wh,
        float* __restrict__ zpart, float* __restrict__ hpart) {
    int t = threadIdx.x;
    int n = blockIdx.x * 256 + t;
    int k0 = blockIdx.y * 32;
    __shared__ float sg[8][32];
    {
        int b = t >> 5, k = t & 31;
        float s = bias[k0 + k];
        #pragma unroll 8
        for (int p = 0; p < 32; ++p) s += partIn[((size_t)p * 8 + b) * 1024 + k0 + k];
        sg[b][k] = s;
    }
    __syncthreads();
    float az[8] = {}, ah[8] = {};
    #pragma unroll
    for (int k = 0; k < 32; ++k) {
        size_t o = (size_t)(k0 + k) * 1024 + n;
        float wz = Wz[o];
        float wh = Wh[o];
        #pragma unroll
        for (int b = 0; b < 8; ++b) { az[b] += sg[b][k] * wz; ah[b] += sg[b][k] * wh; }
    }
    #pragma unroll
    for (int b = 0; b < 8; ++b) {
        size_t o = ((size_t)blockIdx.y * 8 + b) * 1024 + n;
        zpart[o] = az[b];
        hpart[o] = ah[b];
    }
}

// ---------- k3b reduce + gate + h-LayerNorm fused (grid 8, one block per b) ----------
__global__ __launch_bounds__(256) void k3b_red_ln(const float* __restrict__ zpart,
        const float* __restrict__ hpart, const float* __restrict__ bz,
        const float* __restrict__ bh, const float* __restrict__ state,
        const float* __restrict__ lg, const float* __restrict__ lb,
        float* __restrict__ hnew, float* __restrict__ outh,
        float* __restrict__ shb, float* __restrict__ shhb) {
    int b = blockIdx.x, tid = threadIdx.x;
    int w = tid >> 6, lane = tid & 63;
    __shared__ float rbuf[4][2];
    float hp[4];
    float sum = 0.f, ssq = 0.f;
    #pragma unroll
    for (int q = 0; q < 4; ++q) {
        int n = q * 256 + tid;
        float az = bz[n], ah = bh[n];
        #pragma unroll 8
        for (int p = 0; p < 32; ++p) {
            size_t o = ((size_t)p * 8 + b) * 1024 + n;
            az += zpart[o];
            ah += hpart[o];
        }
        float z = 1.f / (1.f + expf(-az));
        float hc = tanhf(ah);
        float v = (1.f - z) * state[(size_t)b * 1024 + n] + z * hc;
        hp[q] = v; sum += v; ssq += v * v;
    }
    #pragma unroll
    for (int m = 1; m < 64; m <<= 1) { sum += __shfl_xor(sum, m); ssq += __shfl_xor(ssq, m); }
    if (lane == 0) { rbuf[w][0] = sum; rbuf[w][1] = ssq; }
    __syncthreads();
    sum = rbuf[0][0] + rbuf[1][0] + rbuf[2][0] + rbuf[3][0];
    ssq = rbuf[0][1] + rbuf[1][1] + rbuf[2][1] + rbuf[3][1];
    float mean = sum * (1.f / 1024.f);
    float var = ssq * (1.f / 1024.f) - mean * mean;
    float rstd = rsqrtf(var + EPS_);
    float s2 = 0.f, q2 = 0.f;
    #pragma unroll
    for (int q = 0; q < 4; ++q) {
        int n = q * 256 + tid;
        float h = (hp[q] - mean) * rstd * lg[n] + lb[n];
        hnew[(size_t)b * 1024 + n] = h;
        outh[(size_t)b * 1024 + n] = h;
        s2 += h; q2 += h * h;
    }
    #pragma unroll
    for (int m = 1; m < 64; m <<= 1) { s2 += __shfl_xor(s2, m); q2 += __shfl_xor(q2, m); }
    __syncthreads();
    if (lane == 0) { rbuf[w][0] = s2; rbuf[w][1] = q2; }
    __syncthreads();
    if (tid == 0) {
        shb[b] = rbuf[0][0] + rbuf[1][0] + rbuf[2][0] + rbuf[3][0];
        shhb[b] = rbuf[0][1] + rbuf[1][1] + rbuf[2][1] + rbuf[3][1];
    }
}

// ---------- K4b: per-token router-LN scalars pt=rstd, qt=-m*rstd ----------
__global__ __launch_bounds__(256) void k4b(const float* __restrict__ sx,
        const float* __restrict__ sxx, const float* __restrict__ shb,
        const float* __restrict__ shhb, float* __restrict__ pt, float* __restrict__ qt) {
    int t = blockIdx.x * 256 + threadIdx.x;   // grid 64
    int b = t >> 11;
    float m = (sx[t] + shb[b]) * (1.f / 2048.f);
    float var = (sxx[t] + shhb[b]) * (1.f / 2048.f) - m * m;
    float rstd = rsqrtf(var + EPS_);
    pt[t] = rstd;
    qt[t] = -m * rstd;
}

// ---------- K5 (round-2 exact structure + slot-swizzle):
//   split-bf16 MFMA GEMM u = x @ W', 128x128 tile, BK=64, 2-barrier K-loop,
//   fused GELU + partial logits; epilogue constants PRECOMPUTED (VGPR ~108) ----------
__device__ __forceinline__ void gl16(const void* g, void* l) {
    __builtin_amdgcn_global_load_lds((const __attribute__((address_space(1))) void*)g,
                                     (__attribute__((address_space(3))) void*)l, 16, 0, 0);
}

__global__ __launch_bounds__(256, 1) void k5_gemm(
        const u16* __restrict__ xhi, const u16* __restrict__ xlo,
        const u16* __restrict__ whiT, const u16* __restrict__ wloT,
        const float* __restrict__ pt, const float* __restrict__ qt,
        const float* __restrict__ vmat, const float* __restrict__ c1,
        const float* __restrict__ dvec, const float* __restrict__ rw2,
        float* __restrict__ lpart) {
    __shared__ unsigned char smem[66048];
    u16* sAh = (u16*)smem;
    u16* sAl = sAh + 128 * 64;
    u16* sBh = sAl + 128 * 64;
    u16* sBl = sBh + 128 * 64;
    float* shid = (float*)smem;   // reused after main loop: [128][129]

    int nb = blockIdx.x, mb = blockIdx.y;   // (8, 128)
    int tid = threadIdx.x;
    int lane = tid & 63, wid = tid >> 6;
    int wm = wid >> 1, wn = wid & 1;
    int l16 = lane & 15, lq = lane >> 4;

    f32x4 acc[4][4] = {};

    size_t aBase = (size_t)mb * 128 * 1024;
    size_t bBase = (size_t)nb * 128 * 1024;

    for (int kb = 0; kb < 16; ++kb) {
        __syncthreads();
        #pragma unroll
        for (int i = 0; i < 4; ++i) {
            int chunk = tid + 256 * i;
            int row = chunk >> 3, c8 = chunk & 7;
            int s8 = c8 ^ (row & 7);            // involution slot-swizzle (16B granules)
            size_t go = (size_t)row * 1024 + (size_t)kb * 64 + s8 * 8;
            int lo = chunk * 16;                // linear LDS dest (gl16 constraint)
            gl16(xhi + aBase + go, (char*)sAh + lo);
            gl16(xlo + aBase + go, (char*)sAl + lo);
            gl16(whiT + bBase + go, (char*)sBh + lo);
            gl16(wloT + bBase + go, (char*)sBl + lo);
        }
        asm volatile("s_waitcnt vmcnt(0)" ::: "memory");
        __syncthreads();
        #pragma unroll
        for (int kk = 0; kk < 2; ++kk) {
            bf16x8 ah[4], al[4], bh[4], bl[4];
            // swizzled read slot: within a frag, row&7 == l16&7
            int sl = ((kk * 4 + lq) ^ (l16 & 7)) * 8;
            #pragma unroll
            for (int f = 0; f < 4; ++f) {
                int ar = wm * 64 + f * 16 + l16;
                int br = wn * 64 + f * 16 + l16;
                ah[f] = *(const bf16x8*)&sAh[ar * 64 + sl];
                al[f] = *(const bf16x8*)&sAl[ar * 64 + sl];
                bh[f] = *(const bf16x8*)&sBh[br * 64 + sl];
                bl[f] = *(const bf16x8*)&sBl[br * 64 + sl];
            }
            #pragma unroll
            for (int mf = 0; mf < 4; ++mf)
                #pragma unroll
                for (int nf = 0; nf < 4; ++nf) {
                    acc[mf][nf] = __builtin_amdgcn_mfma_f32_16x16x32_bf16(ah[mf], bh[nf], acc[mf][nf], 0, 0, 0);
                    acc[mf][nf] = __builtin_amdgcn_mfma_f32_16x16x32_bf16(ah[mf], bl[nf], acc[mf][nf], 0, 0, 0);
                    acc[mf][nf] = __builtin_amdgcn_mfma_f32_16x16x32_bf16(al[mf], bh[nf], acc[mf][nf], 0, 0, 0);
                }
        }
    }
    __syncthreads();

    // epilogue: hid = gelu(pt*(u+v) + qt*c1 + dvec) -> LDS
    int token0 = mb * 128;
    int bidx = token0 >> 11;
    const float* vrow = vmat + (size_t)bidx * 1024;
    float vn[4], c1n[4], dn[4];
    #pragma unroll
    for (int nf = 0; nf < 4; ++nf) {
        int n = nb * 128 + wn * 64 + nf * 16 + l16;
        vn[nf] = vrow[n]; c1n[nf] = c1[n]; dn[nf] = dvec[n];
    }
    #pragma unroll
    for (int mf = 0; mf < 4; ++mf) {
        #pragma unroll
        for (int r = 0; r < 4; ++r) {
            int rowl = wm * 64 + mf * 16 + lq * 4 + r;
            float p = pt[token0 + rowl];
            float q = qt[token0 + rowl];
            #pragma unroll
            for (int nf = 0; nf < 4; ++nf) {
                int coll = wn * 64 + nf * 16 + l16;
                float pre = p * (acc[mf][nf][r] + vn[nf]) + q * c1n[nf] + dn[nf];
                float hid = 0.5f * pre * (1.f + erff(pre * 0.70710678118f));
                shid[rowl * 129 + coll] = hid;
            }
        }
    }
    __syncthreads();

    // partial logits for this N-block: [128 tokens][16 heads]
    int r2 = tid >> 1, half = tid & 1;
    const float* w2b = rw2 + (size_t)nb * 128 * 16 + half * 8;
    float a8[8];
    #pragma unroll
    for (int h = 0; h < 8; ++h) a8[h] = 0.f;
    #pragma unroll 8
    for (int j = 0; j < 128; ++j) {
        float hv = shid[r2 * 129 + j];
        float4 w0 = *(const float4*)(w2b + (size_t)j * 16);
        float4 w1 = *(const float4*)(w2b + (size_t)j * 16 + 4);
        a8[0] += hv * w0.x; a8[1] += hv * w0.y; a8[2] += hv * w0.z; a8[3] += hv * w0.w;
        a8[4] += hv * w1.x; a8[5] += hv * w1.y; a8[6] += hv * w1.z; a8[7] += hv * w1.w;
    }
    float* lp = lpart + ((size_t)nb * T_ + token0 + r2) * 16 + half * 8;
    #pragma unroll
    for (int h = 0; h < 8; ++h) lp[h] = a8[h];
}

// ---------- K6: sum partials -> logits -> softmax -> top4 renorm -> alpha, entropy partials ----------
__global__ __launch_bounds__(256) void k6(const float* __restrict__ lpart,
        const float* __restrict__ rb2, float* __restrict__ alpha_out,
        float* __restrict__ entpart) {
    int blk = blockIdx.x;   // 1024
    int tid = threadIdx.x;
    int token = blk * 16 + (tid >> 4);
    int h = tid & 15;
    float lg = rb2[h];
    #pragma unroll
    for (int p = 0; p < 8; ++p) lg += lpart[((size_t)p * T_ + token) * 16 + h];

    float mx = lg;
    #pragma unroll
    for (int m = 1; m < 16; m <<= 1) mx = fmaxf(mx, __shfl_xor(mx, m));
    float e = expf(lg - mx);
    float sum = e;
    #pragma unroll
    for (int m = 1; m < 16; m <<= 1) sum += __shfl_xor(sum, m);
    float a0 = e / sum;

    float work = lg;
    bool sel = false;
    #pragma unroll
    for (int it = 0; it < 4; ++it) {
        float bv = work; int bi = h;
        #pragma unroll
        for (int m = 1; m < 16; m <<= 1) {
            float ov = __shfl_xor(bv, m); int oi = __shfl_xor(bi, m);
            if (ov > bv || (ov == bv && oi < bi)) { bv = ov; bi = oi; }
        }
        if (h == bi) { sel = true; work = -1e30f; }
    }
    float am = sel ? a0 : 0.f;
    float den = am;
    #pragma unroll
    for (int m = 1; m < 16; m <<= 1) den += __shfl_xor(den, m);
    den = fmaxf(den, 1e-12f);
    float a = am / den;
    alpha_out[(size_t)token * 16 + h] = a;

    float term = a * logf(fmaxf(a, 1e-12f));
    #pragma unroll
    for (int m = 1; m < 64; m <<= 1) term += __shfl_xor(term, m);
    __shared__ float tw[4];
    if ((tid & 63) == 0) tw[tid >> 6] = term;
    __syncthreads();
    if (tid == 0) entpart[blk] = tw[0] + tw[1] + tw[2] + tw[3];
}

// ---------- K7: entropy finalize ----------
__global__ __launch_bounds__(256) void k7(const float* __restrict__ entpart,
        float* __restrict__ out_ent) {
    int tid = threadIdx.x;
    float s = 0.f;
    for (int i = tid; i < 1024; i += 256) s += entpart[i];
    #pragma unroll
    for (int m = 1; m < 64; m <<= 1) s += __shfl_xor(s, m);
    __shared__ float tw[4];
    if ((tid & 63) == 0) tw[tid >> 6] = s;
    __syncthreads();
    if (tid == 0) out_ent[0] = -(tw[0] + tw[1] + tw[2] + tw[3]) * (1.f / (float)T_);
}

extern "C" void kernel_launch(void* const* d_in, const int* in_sizes, int n_in,
                              void* d_out, int out_size, void* d_ws, size_t ws_size,
                              hipStream_t stream) {
    const float* x     = (const float*)d_in[0];
    const float* state = (const float*)d_in[1];
    const float* pg    = (const float*)d_in[2];
    const float* pbv   = (const float*)d_in[3];
    const float* inpw  = (const float*)d_in[4];
    const float* inpb  = (const float*)d_in[5];
    const float* wzw   = (const float*)d_in[6];
    const float* wzb   = (const float*)d_in[7];
    const float* whw   = (const float*)d_in[8];
    const float* whb   = (const float*)d_in[9];
    const float* lnhg  = (const float*)d_in[10];
    const float* lnhb  = (const float*)d_in[11];
    const float* rlng  = (const float*)d_in[12];
    const float* rlnb  = (const float*)d_in[13];
    const float* rw1   = (const float*)d_in[14];
    const float* rb1   = (const float*)d_in[15];
    const float* rw2   = (const float*)d_in[16];
    const float* rb2   = (const float*)d_in[17];
    float* out = (float*)d_out;
    (void)in_sizes; (void)n_in; (void)out_size; (void)ws_size;

    char* base = (char*)d_ws;
    size_t off = 0;
    auto alloc = [&](size_t bytes) -> char* {
        char* p = base + off;
        off = (off + bytes + 255) & ~(size_t)255;
        return p;
    };
    u16*   xhi    = (u16*)alloc((size_t)T_ * D_ * 2);
    u16*   xlo    = (u16*)alloc((size_t)T_ * D_ * 2);
    u16*   whiT   = (u16*)alloc((size_t)D_ * D_ * 2);
    u16*   wloT   = (u16*)alloc((size_t)D_ * D_ * 2);
    float* c1part = (float*)alloc(32 * 1024 * 4);
    float* c2part = (float*)alloc(32 * 1024 * 4);
    float* c1     = (float*)alloc(1024 * 4);
    float* dvec   = (float*)alloc(1024 * 4);
    float* sx     = (float*)alloc((size_t)T_ * 4);
    float* sxx    = (float*)alloc((size_t)T_ * 4);
    float* ptv    = (float*)alloc((size_t)T_ * 4);
    float* qtv    = (float*)alloc((size_t)T_ * 4);
    float* gpart  = (float*)alloc((size_t)8 * 32 * 1024 * 4);
    float* hnew   = (float*)alloc(8 * 1024 * 4);
    float* vmat   = (float*)alloc(8 * 1024 * 4);
    float* shb    = (float*)alloc(256);
    float* shhb   = (float*)alloc(256);
    float* lpart  = (float*)alloc((size_t)8 * T_ * H_ * 4);
    float* entpart= (float*)alloc(1024 * 4);
    float* partA  = (float*)alloc((size_t)32 * 8 * 1024 * 4);   // xctrl partials, then vmat partials
    float* partB  = (float*)alloc((size_t)32 * 8 * 1024 * 4);   // z partials
    float* partC  = (float*)alloc((size_t)32 * 8 * 1024 * 4);   // h partials

    k0a<<<dim3(16, 32), 256, 0, stream>>>(rw1, rlng, rlnb, whiT, wloT, c1part, c2part);
    k0b<<<4, 256, 0, stream>>>(c1part, c2part, rb1, c1, dvec);
    k1<<<256, 256, 0, stream>>>(x, xhi, xlo, sx, sxx, gpart);
    kgemv_g<<<dim3(4, 32), 256, 0, stream>>>(gpart, pg, pbv, inpw, partA);
    kgemv2_f<<<dim3(4, 32), 256, 0, stream>>>(partA, inpb, wzw, whw, partB, partC);
    k3b_red_ln<<<8, 256, 0, stream>>>(partB, partC, wzb, whb, state, lnhg, lnhb,
                                      hnew, out + (size_t)T_ * H_, shb, shhb);
    kgemv_split<<<dim3(4, 32), 256, 0, stream>>>(hnew, rw1 + (size_t)1024 * 1024,
                                                 rlng + 1024, partA);
    kred_bias<<<32, 256, 0, stream>>>(partA, nullptr, vmat);
    k4b<<<64, 256, 0, stream>>>(sx, sxx, shb, shhb, ptv, qtv);
    k5_gemm<<<dim3(8, 128), 256, 0, stream>>>(xhi, xlo, whiT, wloT, ptv, qtv, vmat,
                                              c1, dvec, rw2, lpart);
    k6<<<1024, 256, 0, stream>>>(lpart, rb2, out, entpart);
    k7<<<1, 256, 0, stream>>>(entpart, out + (size_t)T_ * H_ + (size_t)B_ * D_);
}

// Round 8
// 202.981 us; speedup vs baseline: 1.7657x; 1.1249x over previous
//
#include <hip/hip_runtime.h>
#include <hip/hip_bf16.h>
#include <math.h>

typedef unsigned short u16;
typedef __attribute__((ext_vector_type(8))) short bf16x8;
typedef __attribute__((ext_vector_type(4))) float f32x4;
typedef __attribute__((ext_vector_type(4))) unsigned short u16x4;

#define B_ 8
#define S_ 2048
#define T_ 16384
#define D_ 1024
#define H_ 16
#define EPS_ 1e-5f

__device__ __forceinline__ u16 f2bf(float f) {
    __hip_bfloat16 h = __float2bfloat16(f);
    union { __hip_bfloat16 h; u16 u; } cv; cv.h = h; return cv.u;
}
__device__ __forceinline__ float bf2f(u16 u) {
    union { u16 u; __hip_bfloat16 h; } cv; cv.u = u; return __bfloat162float(cv.h);
}

// ---------- K0a: W' = diag(rln_g[:1024])*r_w1[:1024] transposed + split bf16;
//            c1/c2 partials over all 2048 rows ----------
__global__ __launch_bounds__(256) void k0a(const float* __restrict__ rw1,
        const float* __restrict__ rlng, const float* __restrict__ rlnb,
        u16* __restrict__ whiT, u16* __restrict__ wloT,
        float* __restrict__ c1part, float* __restrict__ c2part) {
    int nb = blockIdx.x, kb = blockIdx.y;   // nb<16, kb<32
    int t = threadIdx.x;
    int nl = t & 63, kq = t >> 6;
    int n0 = nb * 64, k0 = kb * 64;
    __shared__ float ld[64][65];
    __shared__ float red[2][4][64];
    float a1 = 0.f, a2 = 0.f;
    #pragma unroll
    for (int r = 0; r < 16; ++r) {
        int kl = r * 4 + kq;
        int k = k0 + kl, n = n0 + nl;
        float w0 = rw1[(size_t)k * 1024 + n];
        ld[kl][nl] = w0;
        a1 += rlng[k] * w0;
        a2 += rlnb[k] * w0;
    }
    red[0][kq][nl] = a1;
    red[1][kq][nl] = a2;
    __syncthreads();
    if (t < 64) {
        c1part[(size_t)kb * 1024 + n0 + t] = red[0][0][t] + red[0][1][t] + red[0][2][t] + red[0][3][t];
        c2part[(size_t)kb * 1024 + n0 + t] = red[1][0][t] + red[1][1][t] + red[1][2][t] + red[1][3][t];
    }
    if (kb < 16) {
        #pragma unroll
        for (int r = 0; r < 16; ++r) {
            int nl2 = r * 4 + kq;
            int k = k0 + nl, n = n0 + nl2;
            float w0 = ld[nl][nl2] * rlng[k];
            u16 hi = f2bf(w0);
            float lo = w0 - bf2f(hi);
            whiT[(size_t)n * 1024 + k] = hi;
            wloT[(size_t)n * 1024 + k] = f2bf(lo);
        }
    }
}

// ---------- K1: pool LN pass over x; per-token sums; x -> split bf16 ----------
__global__ __launch_bounds__(256) void k1(const float* __restrict__ x,
        u16* __restrict__ xhi, u16* __restrict__ xlo,
        float* __restrict__ sx, float* __restrict__ sxx, float* __restrict__ gpart) {
    int blk = blockIdx.x;                  // 256 blocks
    int b = blk >> 5, chunk = blk & 31;
    int tid = threadIdx.x, w = tid >> 6, lane = tid & 63;
    __shared__ float lacc[4][1024];
    float acc[4][4];
    #pragma unroll
    for (int j = 0; j < 4; ++j)
        #pragma unroll
        for (int c = 0; c < 4; ++c) acc[j][c] = 0.f;

    for (int i = 0; i < 16; ++i) {
        int s = chunk * 64 + i * 4 + w;
        size_t tok = (size_t)b * S_ + s;
        size_t base = tok * D_;
        float4 v[4];
        float sum = 0.f, ssq = 0.f;
        #pragma unroll
        for (int j = 0; j < 4; ++j) {
            v[j] = *(const float4*)&x[base + j * 256 + lane * 4];
            sum += v[j].x + v[j].y + v[j].z + v[j].w;
            ssq += v[j].x * v[j].x + v[j].y * v[j].y + v[j].z * v[j].z + v[j].w * v[j].w;
        }
        #pragma unroll
        for (int m = 1; m < 64; m <<= 1) { sum += __shfl_xor(sum, m); ssq += __shfl_xor(ssq, m); }
        float mean = sum * (1.f / 1024.f);
        float var = ssq * (1.f / 1024.f) - mean * mean;
        float rstd = rsqrtf(var + EPS_);
        if (lane == 0) { sx[tok] = sum; sxx[tok] = ssq; }
        #pragma unroll
        for (int j = 0; j < 4; ++j) {
            float xs[4] = { v[j].x, v[j].y, v[j].z, v[j].w };
            u16 hs[4], ls[4];
            #pragma unroll
            for (int c = 0; c < 4; ++c) {
                acc[j][c] += (xs[c] - mean) * rstd;
                u16 h = f2bf(xs[c]);
                hs[c] = h;
                ls[c] = f2bf(xs[c] - bf2f(h));
            }
            size_t o = base + j * 256 + lane * 4;
            *(u16x4*)&xhi[o] = (u16x4){ hs[0], hs[1], hs[2], hs[3] };
            *(u16x4*)&xlo[o] = (u16x4){ ls[0], ls[1], ls[2], ls[3] };
        }
    }
    #pragma unroll
    for (int j = 0; j < 4; ++j)
        #pragma unroll
        for (int c = 0; c < 4; ++c) lacc[w][j * 256 + lane * 4 + c] = acc[j][c];
    __syncthreads();
    for (int q = 0; q < 4; ++q) {
        int n = q * 256 + tid;
        gpart[((size_t)b * 32 + chunk) * 1024 + n] =
            lacc[0][n] + lacc[1][n] + lacc[2][n] + lacc[3][n];
    }
}

// ---------- kgemv_g: fused g-vector build (reduce gpart) + split-K GEMV with inp_w ----------
__global__ __launch_bounds__(256) void kgemv_g(const float* __restrict__ gpart,
        const float* __restrict__ pg, const float* __restrict__ pb,
        const float* __restrict__ W, float* __restrict__ part) {
    int t = threadIdx.x;
    int n = blockIdx.x * 256 + t;
    int k0 = blockIdx.y * 32;
    __shared__ float sg[8][32];
    {
        int b = t >> 5, k = t & 31;
        float s = 0.f;
        #pragma unroll 8
        for (int p = 0; p < 32; ++p) s += gpart[((size_t)b * 32 + p) * 1024 + k0 + k];
        sg[b][k] = s * (1.f / 2048.f) * pg[k0 + k] + pb[k0 + k];
    }
    __syncthreads();
    float acc[8] = {};
    #pragma unroll
    for (int k = 0; k < 32; ++k) {
        float wv = W[(size_t)(k0 + k) * 1024 + n];
        #pragma unroll
        for (int b = 0; b < 8; ++b) acc[b] += sg[b][k] * wv;
    }
    #pragma unroll
    for (int b = 0; b < 8; ++b)
        part[((size_t)blockIdx.y * 8 + b) * 1024 + n] = acc[b];
}

// ---------- split-K GEMV: part[kb][b][n] = sum_{k in slice} in[b][k]*scale[k]*W[k][n] ----------
__global__ __launch_bounds__(256) void kgemv_split(const float* __restrict__ in,
        const float* __restrict__ W, const float* __restrict__ scale,
        float* __restrict__ part) {
    int t = threadIdx.x;
    int n = blockIdx.x * 256 + t;
    int k0 = blockIdx.y * 32;
    __shared__ float sg[8][32];
    {
        int b = t >> 5, k = t & 31;
        float v = in[b * 1024 + k0 + k];
        if (scale) v *= scale[k0 + k];
        sg[b][k] = v;
    }
    __syncthreads();
    float acc[8] = {};
    #pragma unroll
    for (int k = 0; k < 32; ++k) {
        float wv = W[(size_t)(k0 + k) * 1024 + n];
        #pragma unroll
        for (int b = 0; b < 8; ++b) acc[b] += sg[b][k] * wv;
    }
    #pragma unroll
    for (int b = 0; b < 8; ++b)
        part[((size_t)blockIdx.y * 8 + b) * 1024 + n] = acc[b];
}

// ---------- kgemv2_f: fused xctrl reduce(+bias) + dual split-K GEMV for W_z / W_h ----------
__global__ __launch_bounds__(256) void kgemv2_f(const float* __restrict__ partIn,
        const float* __restrict__ bias,
        const float* __restrict__ Wz, const float* __restrict__ Wh,
        float* __restrict__ zpart, float* __restrict__ hpart) {
    int t = threadIdx.x;
    int n = blockIdx.x * 256 + t;
    int k0 = blockIdx.y * 32;
    __shared__ float sg[8][32];
    {
        int b = t >> 5, k = t & 31;
        float s = bias[k0 + k];
        #pragma unroll 8
        for (int p = 0; p < 32; ++p) s += partIn[((size_t)p * 8 + b) * 1024 + k0 + k];
        sg[b][k] = s;
    }
    __syncthreads();
    float az[8] = {}, ah[8] = {};
    #pragma unroll
    for (int k = 0; k < 32; ++k) {
        size_t o = (size_t)(k0 + k) * 1024 + n;
        float wz = Wz[o];
        float wh = Wh[o];
        #pragma unroll
        for (int b = 0; b < 8; ++b) { az[b] += sg[b][k] * wz; ah[b] += sg[b][k] * wh; }
    }
    #pragma unroll
    for (int b = 0; b < 8; ++b) {
        size_t o = ((size_t)blockIdx.y * 8 + b) * 1024 + n;
        zpart[o] = az[b];
        hpart[o] = ah[b];
    }
}

// ---------- k3b reduce + gate + h-LayerNorm fused (grid 8, one block per b) ----------
__global__ __launch_bounds__(256) void k3b_red_ln(const float* __restrict__ zpart,
        const float* __restrict__ hpart, const float* __restrict__ bz,
        const float* __restrict__ bh, const float* __restrict__ state,
        const float* __restrict__ lg, const float* __restrict__ lb,
        float* __restrict__ hnew, float* __restrict__ outh,
        float* __restrict__ shb, float* __restrict__ shhb) {
    int b = blockIdx.x, tid = threadIdx.x;
    int w = tid >> 6, lane = tid & 63;
    __shared__ float rbuf[4][2];
    float hp[4];
    float sum = 0.f, ssq = 0.f;
    #pragma unroll
    for (int q = 0; q < 4; ++q) {
        int n = q * 256 + tid;
        float az = bz[n], ah = bh[n];
        #pragma unroll 8
        for (int p = 0; p < 32; ++p) {
            size_t o = ((size_t)p * 8 + b) * 1024 + n;
            az += zpart[o];
            ah += hpart[o];
        }
        float z = 1.f / (1.f + expf(-az));
        float hc = tanhf(ah);
        float v = (1.f - z) * state[(size_t)b * 1024 + n] + z * hc;
        hp[q] = v; sum += v; ssq += v * v;
    }
    #pragma unroll
    for (int m = 1; m < 64; m <<= 1) { sum += __shfl_xor(sum, m); ssq += __shfl_xor(ssq, m); }
    if (lane == 0) { rbuf[w][0] = sum; rbuf[w][1] = ssq; }
    __syncthreads();
    sum = rbuf[0][0] + rbuf[1][0] + rbuf[2][0] + rbuf[3][0];
    ssq = rbuf[0][1] + rbuf[1][1] + rbuf[2][1] + rbuf[3][1];
    float mean = sum * (1.f / 1024.f);
    float var = ssq * (1.f / 1024.f) - mean * mean;
    float rstd = rsqrtf(var + EPS_);
    float s2 = 0.f, q2 = 0.f;
    #pragma unroll
    for (int q = 0; q < 4; ++q) {
        int n = q * 256 + tid;
        float h = (hp[q] - mean) * rstd * lg[n] + lb[n];
        hnew[(size_t)b * 1024 + n] = h;
        outh[(size_t)b * 1024 + n] = h;
        s2 += h; q2 += h * h;
    }
    #pragma unroll
    for (int m = 1; m < 64; m <<= 1) { s2 += __shfl_xor(s2, m); q2 += __shfl_xor(q2, m); }
    __syncthreads();
    if (lane == 0) { rbuf[w][0] = s2; rbuf[w][1] = q2; }
    __syncthreads();
    if (tid == 0) {
        shb[b] = rbuf[0][0] + rbuf[1][0] + rbuf[2][0] + rbuf[3][0];
        shhb[b] = rbuf[0][1] + rbuf[1][1] + rbuf[2][1] + rbuf[3][1];
    }
}

// ---------- kprep: fold of {vmat reduce, c1/dvec reduce, pt/qt} (grid 100) ----------
__global__ __launch_bounds__(256) void kprep(const float* __restrict__ vpartIn,
        const float* __restrict__ c1part, const float* __restrict__ c2part,
        const float* __restrict__ rb1,
        const float* __restrict__ sx, const float* __restrict__ sxx,
        const float* __restrict__ shb, const float* __restrict__ shhb,
        float* __restrict__ vmat, float* __restrict__ c1, float* __restrict__ dvec,
        float* __restrict__ pt, float* __restrict__ qt) {
    int blk = blockIdx.x, tid = threadIdx.x;
    if (blk < 32) {                 // vmat = reduce vpartIn
        int i = blk * 256 + tid;
        int b = i >> 10, n = i & 1023;
        float s = 0.f;
        #pragma unroll 8
        for (int p = 0; p < 32; ++p) s += vpartIn[((size_t)p * 8 + b) * 1024 + n];
        vmat[i] = s;
    } else if (blk < 36) {          // c1, dvec
        int n = (blk - 32) * 256 + tid;
        float s1 = 0.f, s2 = 0.f;
        for (int p = 0; p < 32; ++p) { s1 += c1part[p * 1024 + n]; s2 += c2part[p * 1024 + n]; }
        c1[n] = s1;
        dvec[n] = s2 + rb1[n];
    } else {                        // pt/qt per token (64 blocks)
        int t = (blk - 36) * 256 + tid;
        int b = t >> 11;
        float m = (sx[t] + shb[b]) * (1.f / 2048.f);
        float var = (sxx[t] + shhb[b]) * (1.f / 2048.f) - m * m;
        float rstd = rsqrtf(var + EPS_);
        pt[t] = rstd;
        qt[t] = -m * rstd;
    }
}

// ---------- K5 (round-7 structure + XCD-bijective remap for A-panel L2 reuse):
//   split-bf16 MFMA GEMM u = x @ W', 128x128 tile, BK=64, 2-barrier K-loop ----------
__device__ __forceinline__ void gl16(const void* g, void* l) {
    __builtin_amdgcn_global_load_lds((const __attribute__((address_space(1))) void*)g,
                                     (__attribute__((address_space(3))) void*)l, 16, 0, 0);
}

__global__ __launch_bounds__(256, 1) void k5_gemm(
        const u16* __restrict__ xhi, const u16* __restrict__ xlo,
        const u16* __restrict__ whiT, const u16* __restrict__ wloT,
        const float* __restrict__ pt, const float* __restrict__ qt,
        const float* __restrict__ vmat, const float* __restrict__ c1,
        const float* __restrict__ dvec, const float* __restrict__ rw2,
        float* __restrict__ lpart) {
    __shared__ unsigned char smem[66048];
    u16* sAh = (u16*)smem;
    u16* sAl = sAh + 128 * 64;
    u16* sBh = sAl + 128 * 64;
    u16* sBl = sBh + 128 * 64;
    float* shid = (float*)smem;   // reused after main loop: [128][129]

    // XCD-bijective remap: XCD x = bid%8 handles mb in [x*16, x*16+16), all nb.
    // Within an XCD, the 8 nb-blocks of one mb are consecutive -> co-resident ->
    // A-panel fetched once into that XCD's L2 and reused 8x.
    int bid = blockIdx.x;                   // 1024
    int x8 = bid & 7, j = bid >> 3;
    int mb = x8 * 16 + (j >> 3);            // 0..127
    int nb = j & 7;                         // 0..7
    int tid = threadIdx.x;
    int lane = tid & 63, wid = tid >> 6;
    int wm = wid >> 1, wn = wid & 1;
    int l16 = lane & 15, lq = lane >> 4;

    f32x4 acc[4][4] = {};

    size_t aBase = (size_t)mb * 128 * 1024;
    size_t bBase = (size_t)nb * 128 * 1024;

    for (int kb = 0; kb < 16; ++kb) {
        __syncthreads();
        #pragma unroll
        for (int i = 0; i < 4; ++i) {
            int chunk = tid + 256 * i;
            int row = chunk >> 3, c8 = chunk & 7;
            int s8 = c8 ^ (row & 7);            // involution slot-swizzle (16B granules)
            size_t go = (size_t)row * 1024 + (size_t)kb * 64 + s8 * 8;
            int lo = chunk * 16;                // linear LDS dest (gl16 constraint)
            gl16(xhi + aBase + go, (char*)sAh + lo);
            gl16(xlo + aBase + go, (char*)sAl + lo);
            gl16(whiT + bBase + go, (char*)sBh + lo);
            gl16(wloT + bBase + go, (char*)sBl + lo);
        }
        asm volatile("s_waitcnt vmcnt(0)" ::: "memory");
        __syncthreads();
        #pragma unroll
        for (int kk = 0; kk < 2; ++kk) {
            bf16x8 ah[4], al[4], bh[4], bl[4];
            // swizzled read slot: within a frag, row&7 == l16&7
            int sl = ((kk * 4 + lq) ^ (l16 & 7)) * 8;
            #pragma unroll
            for (int f = 0; f < 4; ++f) {
                int ar = wm * 64 + f * 16 + l16;
                int br = wn * 64 + f * 16 + l16;
                ah[f] = *(const bf16x8*)&sAh[ar * 64 + sl];
                al[f] = *(const bf16x8*)&sAl[ar * 64 + sl];
                bh[f] = *(const bf16x8*)&sBh[br * 64 + sl];
                bl[f] = *(const bf16x8*)&sBl[br * 64 + sl];
            }
            #pragma unroll
            for (int mf = 0; mf < 4; ++mf)
                #pragma unroll
                for (int nf = 0; nf < 4; ++nf) {
                    acc[mf][nf] = __builtin_amdgcn_mfma_f32_16x16x32_bf16(ah[mf], bh[nf], acc[mf][nf], 0, 0, 0);
                    acc[mf][nf] = __builtin_amdgcn_mfma_f32_16x16x32_bf16(ah[mf], bl[nf], acc[mf][nf], 0, 0, 0);
                    acc[mf][nf] = __builtin_amdgcn_mfma_f32_16x16x32_bf16(al[mf], bh[nf], acc[mf][nf], 0, 0, 0);
                }
        }
    }
    __syncthreads();

    // epilogue: hid = gelu(pt*(u+v) + qt*c1 + dvec) -> LDS
    int token0 = mb * 128;
    int bidx = token0 >> 11;
    const float* vrow = vmat + (size_t)bidx * 1024;
    float vn[4], c1n[4], dn[4];
    #pragma unroll
    for (int nf = 0; nf < 4; ++nf) {
        int n = nb * 128 + wn * 64 + nf * 16 + l16;
        vn[nf] = vrow[n]; c1n[nf] = c1[n]; dn[nf] = dvec[n];
    }
    #pragma unroll
    for (int mf = 0; mf < 4; ++mf) {
        #pragma unroll
        for (int r = 0; r < 4; ++r) {
            int rowl = wm * 64 + mf * 16 + lq * 4 + r;
            float p = pt[token0 + rowl];
            float q = qt[token0 + rowl];
            #pragma unroll
            for (int nf = 0; nf < 4; ++nf) {
                int coll = wn * 64 + nf * 16 + l16;
                float pre = p * (acc[mf][nf][r] + vn[nf]) + q * c1n[nf] + dn[nf];
                float hid = 0.5f * pre * (1.f + erff(pre * 0.70710678118f));
                shid[rowl * 129 + coll] = hid;
            }
        }
    }
    __syncthreads();

    // partial logits for this N-block: [128 tokens][16 heads]
    int r2 = tid >> 1, half = tid & 1;
    const float* w2b = rw2 + (size_t)nb * 128 * 16 + half * 8;
    float a8[8];
    #pragma unroll
    for (int h = 0; h < 8; ++h) a8[h] = 0.f;
    #pragma unroll 8
    for (int j2 = 0; j2 < 128; ++j2) {
        float hv = shid[r2 * 129 + j2];
        float4 w0 = *(const float4*)(w2b + (size_t)j2 * 16);
        float4 w1 = *(const float4*)(w2b + (size_t)j2 * 16 + 4);
        a8[0] += hv * w0.x; a8[1] += hv * w0.y; a8[2] += hv * w0.z; a8[3] += hv * w0.w;
        a8[4] += hv * w1.x; a8[5] += hv * w1.y; a8[6] += hv * w1.z; a8[7] += hv * w1.w;
    }
    float* lp = lpart + ((size_t)nb * T_ + token0 + r2) * 16 + half * 8;
    #pragma unroll
    for (int h = 0; h < 8; ++h) lp[h] = a8[h];
}

// ---------- K6: sum partials -> logits -> softmax -> top4 renorm -> alpha, entropy partials ----------
__global__ __launch_bounds__(256) void k6(const float* __restrict__ lpart,
        const float* __restrict__ rb2, float* __restrict__ alpha_out,
        float* __restrict__ entpart) {
    int blk = blockIdx.x;   // 1024
    int tid = threadIdx.x;
    int token = blk * 16 + (tid >> 4);
    int h = tid & 15;
    float lg = rb2[h];
    #pragma unroll
    for (int p = 0; p < 8; ++p) lg += lpart[((size_t)p * T_ + token) * 16 + h];

    float mx = lg;
    #pragma unroll
    for (int m = 1; m < 16; m <<= 1) mx = fmaxf(mx, __shfl_xor(mx, m));
    float e = expf(lg - mx);
    float sum = e;
    #pragma unroll
    for (int m = 1; m < 16; m <<= 1) sum += __shfl_xor(sum, m);
    float a0 = e / sum;

    float work = lg;
    bool sel = false;
    #pragma unroll
    for (int it = 0; it < 4; ++it) {
        float bv = work; int bi = h;
        #pragma unroll
        for (int m = 1; m < 16; m <<= 1) {
            float ov = __shfl_xor(bv, m); int oi = __shfl_xor(bi, m);
            if (ov > bv || (ov == bv && oi < bi)) { bv = ov; bi = oi; }
        }
        if (h == bi) { sel = true; work = -1e30f; }
    }
    float am = sel ? a0 : 0.f;
    float den = am;
    #pragma unroll
    for (int m = 1; m < 16; m <<= 1) den += __shfl_xor(den, m);
    den = fmaxf(den, 1e-12f);
    float a = am / den;
    alpha_out[(size_t)token * 16 + h] = a;

    float term = a * logf(fmaxf(a, 1e-12f));
    #pragma unroll
    for (int m = 1; m < 64; m <<= 1) term += __shfl_xor(term, m);
    __shared__ float tw[4];
    if ((tid & 63) == 0) tw[tid >> 6] = term;
    __syncthreads();
    if (tid == 0) entpart[blk] = tw[0] + tw[1] + tw[2] + tw[3];
}

// ---------- K7: entropy finalize ----------
__global__ __launch_bounds__(256) void k7(const float* __restrict__ entpart,
        float* __restrict__ out_ent) {
    int tid = threadIdx.x;
    float s = 0.f;
    for (int i = tid; i < 1024; i += 256) s += entpart[i];
    #pragma unroll
    for (int m = 1; m < 64; m <<= 1) s += __shfl_xor(s, m);
    __shared__ float tw[4];
    if ((tid & 63) == 0) tw[tid >> 6] = s;
    __syncthreads();
    if (tid == 0) out_ent[0] = -(tw[0] + tw[1] + tw[2] + tw[3]) * (1.f / (float)T_);
}

extern "C" void kernel_launch(void* const* d_in, const int* in_sizes, int n_in,
                              void* d_out, int out_size, void* d_ws, size_t ws_size,
                              hipStream_t stream) {
    const float* x     = (const float*)d_in[0];
    const float* state = (const float*)d_in[1];
    const float* pg    = (const float*)d_in[2];
    const float* pbv   = (const float*)d_in[3];
    const float* inpw  = (const float*)d_in[4];
    const float* inpb  = (const float*)d_in[5];
    const float* wzw   = (const float*)d_in[6];
    const float* wzb   = (const float*)d_in[7];
    const float* whw   = (const float*)d_in[8];
    const float* whb   = (const float*)d_in[9];
    const float* lnhg  = (const float*)d_in[10];
    const float* lnhb  = (const float*)d_in[11];
    const float* rlng  = (const float*)d_in[12];
    const float* rlnb  = (const float*)d_in[13];
    const float* rw1   = (const float*)d_in[14];
    const float* rb1   = (const float*)d_in[15];
    const float* rw2   = (const float*)d_in[16];
    const float* rb2   = (const float*)d_in[17];
    float* out = (float*)d_out;
    (void)in_sizes; (void)n_in; (void)out_size; (void)ws_size;

    char* base = (char*)d_ws;
    size_t off = 0;
    auto alloc = [&](size_t bytes) -> char* {
        char* p = base + off;
        off = (off + bytes + 255) & ~(size_t)255;
        return p;
    };
    u16*   xhi    = (u16*)alloc((size_t)T_ * D_ * 2);
    u16*   xlo    = (u16*)alloc((size_t)T_ * D_ * 2);
    u16*   whiT   = (u16*)alloc((size_t)D_ * D_ * 2);
    u16*   wloT   = (u16*)alloc((size_t)D_ * D_ * 2);
    float* c1part = (float*)alloc(32 * 1024 * 4);
    float* c2part = (float*)alloc(32 * 1024 * 4);
    float* c1     = (float*)alloc(1024 * 4);
    float* dvec   = (float*)alloc(1024 * 4);
    float* sx     = (float*)alloc((size_t)T_ * 4);
    float* sxx    = (float*)alloc((size_t)T_ * 4);
    float* ptv    = (float*)alloc((size_t)T_ * 4);
    float* qtv    = (float*)alloc((size_t)T_ * 4);
    float* gpart  = (float*)alloc((size_t)8 * 32 * 1024 * 4);
    float* hnew   = (float*)alloc(8 * 1024 * 4);
    float* vmat   = (float*)alloc(8 * 1024 * 4);
    float* shb    = (float*)alloc(256);
    float* shhb   = (float*)alloc(256);
    float* lpart  = (float*)alloc((size_t)8 * T_ * H_ * 4);
    float* entpart= (float*)alloc(1024 * 4);
    float* partA  = (float*)alloc((size_t)32 * 8 * 1024 * 4);   // xctrl partials, then vmat partials
    float* partB  = (float*)alloc((size_t)32 * 8 * 1024 * 4);   // z partials
    float* partC  = (float*)alloc((size_t)32 * 8 * 1024 * 4);   // h partials

    k0a<<<dim3(16, 32), 256, 0, stream>>>(rw1, rlng, rlnb, whiT, wloT, c1part, c2part);
    k1<<<256, 256, 0, stream>>>(x, xhi, xlo, sx, sxx, gpart);
    kgemv_g<<<dim3(4, 32), 256, 0, stream>>>(gpart, pg, pbv, inpw, partA);
    kgemv2_f<<<dim3(4, 32), 256, 0, stream>>>(partA, inpb, wzw, whw, partB, partC);
    k3b_red_ln<<<8, 256, 0, stream>>>(partB, partC, wzb, whb, state, lnhg, lnhb,
                                      hnew, out + (size_t)T_ * H_, shb, shhb);
    kgemv_split<<<dim3(4, 32), 256, 0, stream>>>(hnew, rw1 + (size_t)1024 * 1024,
                                                 rlng + 1024, partA);
    kprep<<<100, 256, 0, stream>>>(partA, c1part, c2part, rb1, sx, sxx, shb, shhb,
                                   vmat, c1, dvec, ptv, qtv);
    k5_gemm<<<1024, 256, 0, stream>>>(xhi, xlo, whiT, wloT, ptv, qtv, vmat,
                                      c1, dvec, rw2, lpart);
    k6<<<1024, 256, 0, stream>>>(lpart, rb2, out, entpart);
    k7<<<1, 256, 0, stream>>>(entpart, out + (size_t)T_ * H_ + (size_t)B_ * D_);
}